// Round 2
// baseline (396.386 us; speedup 1.0000x reference)
//
#include <hip/hip_runtime.h>
#include <cstddef>
#include <cstdint>

using half4v   = __attribute__((ext_vector_type(4))) _Float16;
using half8    = __attribute__((ext_vector_type(8))) _Float16;
using floatx4  = __attribute__((ext_vector_type(4))) float;
using floatx16 = __attribute__((ext_vector_type(16))) float;
using uintx4   = __attribute__((ext_vector_type(4))) unsigned;

#define B_   2
#define NQ_  2048
#define DM   1024
#define NH_  16
#define DH_  64
#define KITERS 16   // NKV / 128

// async global->LDS, 16B per lane. LDS dest = wave-uniform base + lane*16.
__device__ __forceinline__ void async16(const _Float16* g, _Float16* l) {
    __builtin_amdgcn_global_load_lds(
        (const __attribute__((address_space(1))) unsigned int*)g,
        (__attribute__((address_space(3))) unsigned int*)l, 16, 0, 0);
}

// RNE pack 2 f32 -> u32 of 2 f16 (matches previous numerics; pkrtz would bias).
__device__ __forceinline__ unsigned pkh(float a, float b) {
    union { _Float16 h[2]; unsigned u; } x;
    x.h[0] = (_Float16)a; x.h[1] = (_Float16)b;
    return x.u;
}

// ---------------------------------------------------------------------------
// Fused fp32 -> fp16 convert for all 6 tensors (1 launch).
// ---------------------------------------------------------------------------
__global__ __launch_bounds__(256) void cvt_all(
        const float* __restrict__ q,  const float* __restrict__ kv,
        const float* __restrict__ wq, const float* __restrict__ wk,
        const float* __restrict__ wv, const float* __restrict__ wo,
        _Float16* __restrict__ dq,  _Float16* __restrict__ dkv,
        _Float16* __restrict__ dwq, _Float16* __restrict__ dwk,
        _Float16* __restrict__ dwv, _Float16* __restrict__ dwo) {
    int blk = blockIdx.x;
    const float* s;
    _Float16* d;
    int base;
    if (blk < 2048)      { s = q;  d = dq;  base = blk; }
    else if (blk < 4096) { s = kv; d = dkv; base = blk - 2048; }
    else if (blk < 4608) { s = wq; d = dwq; base = blk - 4096; }
    else if (blk < 5120) { s = wk; d = dwk; base = blk - 4608; }
    else if (blk < 5632) { s = wv; d = dwv; base = blk - 5120; }
    else                 { s = wo; d = dwo; base = blk - 5632; }
    int i = base * 256 + threadIdx.x;
    const float4* s4 = (const float4*)s;
    float4 a = s4[2 * i], b = s4[2 * i + 1];
    half8 h;
    h[0] = (_Float16)a.x; h[1] = (_Float16)a.y; h[2] = (_Float16)a.z; h[3] = (_Float16)a.w;
    h[4] = (_Float16)b.x; h[5] = (_Float16)b.y; h[6] = (_Float16)b.z; h[7] = (_Float16)b.w;
    ((half8*)d)[i] = h;
}

// ---------------------------------------------------------------------------
// Fused QKV projection GEMM, 768 blocks (3/CU resident). (unchanged)
// ---------------------------------------------------------------------------
__global__ __launch_bounds__(256, 3) void proj_qkv(
        const _Float16* __restrict__ q16, const _Float16* __restrict__ kv16,
        const _Float16* __restrict__ wqp, const _Float16* __restrict__ wkp,
        const _Float16* __restrict__ wvp,
        const float* __restrict__ bqp, const float* __restrict__ bkp,
        const float* __restrict__ bvp,
        _Float16* __restrict__ qh, _Float16* __restrict__ kh,
        _Float16* __restrict__ vt) {
    __shared__ _Float16 As[128 * 64];   // 16 KB
    __shared__ _Float16 Bs[128 * 64];   // 16 KB

    const int which = blockIdx.x >> 8;
    const int sub = blockIdx.x & 255;
    const _Float16* A = (which == 0) ? q16 : kv16;
    const _Float16* W = (which == 0) ? wqp : (which == 1) ? wkp : wvp;
    const float* bias = (which == 0) ? bqp : (which == 1) ? bkp : bvp;

    const int t = threadIdx.x;
    const int w = t >> 6, lane = t & 63;
    const int r16 = lane & 15, quad = lane >> 4;
    const int bm = (sub & 7) * 4 + ((sub >> 3) & 3);
    const int bn = sub >> 5;
    const int m0 = bm * 128, n0 = bn * 128;
    const int wm = w >> 1, wn = w & 1;

    floatx4 acc[4][4];
#pragma unroll
    for (int i = 0; i < 4; i++)
#pragma unroll
        for (int j = 0; j < 4; j++)
#pragma unroll
            for (int r = 0; r < 4; r++) acc[i][j][r] = 0.f;

    const int ph0 = quad ^ (r16 & 7), ph1 = ph0 ^ 4;

    for (int k0 = 0; k0 < DM; k0 += 64) {
        __syncthreads();
#pragma unroll
        for (int i = 0; i < 4; i++) {
            int P = i * 256 + t;
            int m = P >> 3, c = (P & 7) ^ (m & 7);
            async16(A + (size_t)(m0 + m) * DM + k0 + c * 8, &As[P * 8]);
            async16(W + (size_t)(n0 + m) * DM + k0 + c * 8, &Bs[P * 8]);
        }
        asm volatile("s_waitcnt vmcnt(0)" ::: "memory");
        __syncthreads();

        half8 af[4][2], bf[4][2];
#pragma unroll
        for (int mi = 0; mi < 4; mi++) {
            int m = wm * 64 + mi * 16 + r16;
            af[mi][0] = ((const half8*)As)[m * 8 + ph0];
            af[mi][1] = ((const half8*)As)[m * 8 + ph1];
        }
#pragma unroll
        for (int ni = 0; ni < 4; ni++) {
            int n = wn * 64 + ni * 16 + r16;
            bf[ni][0] = ((const half8*)Bs)[n * 8 + ph0];
            bf[ni][1] = ((const half8*)Bs)[n * 8 + ph1];
        }
#pragma unroll
        for (int kd = 0; kd < 2; kd++)
#pragma unroll
            for (int mi = 0; mi < 4; mi++)
#pragma unroll
                for (int ni = 0; ni < 4; ni++)
                    acc[mi][ni] = __builtin_amdgcn_mfma_f32_16x16x32_f16(
                        af[mi][kd], bf[ni][kd], acc[mi][ni], 0, 0, 0);
    }

    if (which < 2) {
        _Float16* C = (which == 0) ? qh : kh;
        const float esc = (which == 0) ? 0.125f : 1.0f;
#pragma unroll
        for (int mi = 0; mi < 4; mi++)
#pragma unroll
            for (int r = 0; r < 4; r++) {
                int row = m0 + wm * 64 + mi * 16 + quad * 4 + r;
#pragma unroll
                for (int ni = 0; ni < 4; ni++) {
                    int col = n0 + wn * 64 + ni * 16 + r16;
                    C[(size_t)row * DM + col] = (_Float16)((acc[mi][ni][r] + bias[col]) * esc);
                }
            }
    } else {
#pragma unroll
        for (int mi = 0; mi < 4; mi++) {
            int krow = m0 + wm * 64 + mi * 16 + quad * 4;
            int bb = krow >> 11, kk = krow & 2047;
#pragma unroll
            for (int ni = 0; ni < 4; ni++) {
                int col = n0 + wn * 64 + ni * 16 + r16;
                int hh = col >> 6, dd = col & 63;
                float bv = bias[col];
                half4v pk;
#pragma unroll
                for (int r = 0; r < 4; r++) pk[r] = (_Float16)(acc[mi][ni][r] + bv);
                *(half4v*)&vt[((size_t)((bb * NH_ + hh) * DH_ + dd)) * NQ_ + kk] = pk;
            }
        }
    }
}

// ---------------------------------------------------------------------------
// Flash attention, fixed-max softmax. R2 restructure for LATENCY (R1 showed
// LDS-BW cut was neutral: latency/occupancy-bound at 16 waves/CU).
//  - 512-thread blocks (8 waves = 2wq x 4wk over 64q x 128k step), grid 1024
//    -> 32 waves/CU (8/SIMD, was 4/SIMD). __launch_bounds__(512,8) caps VGPR 64.
//  - mfma 32x32x16: wave computes S^T 32k x 32q in ONE 16-reg frag.
//  - P never touches LDS: pack pairs (RNE) + __shfl_xor(,32) half-exchange
//    builds the PV B-frag in registers (removes P write->wait->read chain).
//  - K/V single-buffered (128k per iter): V staged during QK^T, K(i+1) staged
//    during PV -> every vmcnt(0) drain is covered by a compute phase.
//  - Q frags re-read from LDS per step (saves 16 persistent VGPR).
//  - k-split x4 merged in epilogue via XOR-swizzled f32 LDS regions (l and O
//    are additive under fixed-max softmax).
// LDS: Ks 16KB + Vs 16KB + Qs 8KB = 40KB -> 4 blocks/CU.
// ---------------------------------------------------------------------------
__global__ __launch_bounds__(512, 8) void attn_mfma(const _Float16* __restrict__ Qg,
                                                    const _Float16* __restrict__ Kg,
                                                    const _Float16* __restrict__ Vt,
                                                    _Float16* __restrict__ Og) {
    __shared__ _Float16 Ks[128 * 64];  // 16 KB: [128 k][64 dh], chunk^(row&7)
    __shared__ _Float16 Vs[64 * 128];  // 16 KB: [64 d][128 k], chunk^(row&15)
    __shared__ _Float16 Qs[64 * 64];   //  8 KB: [64 q][64 dh], chunk^(row&7)

    const int t = threadIdx.x, w = t >> 6, lane = t & 63;
    const int l31 = lane & 31, hi = lane >> 5;
    const int wq = w >> 2, wk = w & 3;
    const int blk = blockIdx.x;
    const int bh = (blk & 7) * 4 + ((blk >> 3) & 3);
    const int qt = blk >> 5;                      // 0..31
    const int b = bh >> 4, h = bh & 15;

    const _Float16* qbase = Qg + (size_t)(b * NQ_ + qt * 64) * DM + h * DH_;
    const _Float16* kbase = Kg + (size_t)(b * NQ_) * DM + h * DH_;
    const _Float16* vbase = Vt + (size_t)bh * DH_ * NQ_;

    // prologue: stage Q (64x64, one 16B/thread round) + K tile 0 (128x64)
    {
        int m = t >> 3, c = (t & 7) ^ (m & 7);
        async16(qbase + (size_t)m * DM + c * 8, &Qs[t * 8]);
#pragma unroll
        for (int r = 0; r < 2; r++) {
            int P = r * 512 + t;
            int km = P >> 3, kc = (P & 7) ^ (km & 7);
            async16(kbase + (size_t)km * DM + kc * 8, &Ks[P * 8]);
        }
    }
    asm volatile("s_waitcnt vmcnt(0)" ::: "memory");
    __syncthreads();

    floatx16 oacc0, oacc1;
#pragma unroll
    for (int r = 0; r < 16; r++) { oacc0[r] = 0.f; oacc1[r] = 0.f; }
    float lacc = 0.f;

    const int qrow = wq * 32 + l31;
    const int krow = wk * 32 + l31;

    for (int i = 0; i < KITERS; i++) {
        // stage V(i): [64 d][128 k]; Vs free (PV(i-1) reads done before barrier)
#pragma unroll
        for (int r = 0; r < 2; r++) {
            int P = r * 512 + t;
            int vm = P >> 4, vc = (P & 15) ^ (vm & 15);
            async16(vbase + (size_t)vm * NQ_ + i * 128 + vc * 8, &Vs[P * 8]);
        }

        // S^T[32k x 32q] = K . Q^T  (A-frag rows = k, B-frag cols = q)
        floatx16 sacc;
#pragma unroll
        for (int r = 0; r < 16; r++) sacc[r] = 0.f;
#pragma unroll
        for (int step = 0; step < 4; step++) {
            half8 kf = ((const half8*)Ks)[krow * 8 + ((step * 2 + hi) ^ (l31 & 7))];
            half8 qf = ((const half8*)Qs)[qrow * 8 + ((step * 2 + hi) ^ (l31 & 7))];
            sacc = __builtin_amdgcn_mfma_f32_32x32x16_f16(kf, qf, sacc, 0, 0, 0);
        }

        // softmax (fixed max): exp in place, accumulate l
#pragma unroll
        for (int r = 0; r < 16; r++) sacc[r] = __expf(sacc[r]);
#pragma unroll
        for (int r = 0; r < 16; r++) lacc += sacc[r];

        // P -> PV B-frags, fully in registers. For each kstep (16 k-rows):
        // lane needs rows hi*8+j; own regs give half, partner lane (^32) the rest.
        half8 pf0, pf1;
        {
            unsigned a0 = pkh(sacc[0], sacc[1]),  a1 = pkh(sacc[2], sacc[3]);
            unsigned b0 = pkh(sacc[4], sacc[5]),  b1 = pkh(sacc[6], sacc[7]);
            unsigned s0 = hi ? a0 : b0, s1 = hi ? a1 : b1;
            unsigned r0 = (unsigned)__shfl_xor((int)s0, 32);
            unsigned r1 = (unsigned)__shfl_xor((int)s1, 32);
            union { unsigned u[4]; half8 h; } pu;
            pu.u[0] = hi ? r0 : a0; pu.u[1] = hi ? r1 : a1;
            pu.u[2] = hi ? b0 : r0; pu.u[3] = hi ? b1 : r1;
            pf0 = pu.h;
        }
        {
            unsigned a0 = pkh(sacc[8], sacc[9]),   a1 = pkh(sacc[10], sacc[11]);
            unsigned b0 = pkh(sacc[12], sacc[13]), b1 = pkh(sacc[14], sacc[15]);
            unsigned s0 = hi ? a0 : b0, s1 = hi ? a1 : b1;
            unsigned r0 = (unsigned)__shfl_xor((int)s0, 32);
            unsigned r1 = (unsigned)__shfl_xor((int)s1, 32);
            union { unsigned u[4]; half8 h; } pu;
            pu.u[0] = hi ? r0 : a0; pu.u[1] = hi ? r1 : a1;
            pu.u[2] = hi ? b0 : r0; pu.u[3] = hi ? b1 : r1;
            pf1 = pu.h;
        }

        asm volatile("s_waitcnt vmcnt(0)" ::: "memory");  // V(i) landed (only V outstanding)
        __syncthreads();                                  // all waves: V ready, Ks reads done

        if (i + 1 < KITERS) {   // stage K(i+1) during PV
#pragma unroll
            for (int r = 0; r < 2; r++) {
                int P = r * 512 + t;
                int km = P >> 3, kc = (P & 7) ^ (km & 7);
                async16(kbase + (size_t)((i + 1) * 128 + km) * DM + kc * 8, &Ks[P * 8]);
            }
        }

        // O^T[64d x 32q] += V^T . P^T  over this wave's 32 k
#pragma unroll
        for (int kstep = 0; kstep < 2; kstep++) {
            half8 pfk = kstep ? pf1 : pf0;
            {
                half8 vf = ((const half8*)Vs)[(0 * 32 + l31) * 16 + ((wk * 4 + kstep * 2 + hi) ^ (l31 & 15))];
                oacc0 = __builtin_amdgcn_mfma_f32_32x32x16_f16(vf, pfk, oacc0, 0, 0, 0);
            }
            {
                half8 vf = ((const half8*)Vs)[(1 * 32 + l31) * 16 + ((wk * 4 + kstep * 2 + hi) ^ (l31 & 15))];
                oacc1 = __builtin_amdgcn_mfma_f32_32x32x16_f16(vf, pfk, oacc1, 0, 0, 0);
            }
        }

        asm volatile("s_waitcnt vmcnt(0)" ::: "memory");  // K(i+1) landed
        __syncthreads();                                  // Vs reads done -> V(i+1) stageable
    }

    // ---- epilogue: merge 4 wk partials (l and O additive), normalize, store.
    // Regions (f32, [32 q][64 d], elem idx = q*64 + (d ^ q), 8KB each):
    //   RA[wq] in Ks, RB[wq] in Vs. Lb (l partials) in Qs.
    float* Ksf = (float*)Ks;
    float* Vsf = (float*)Vs;
    float* Lb  = (float*)Qs;   // [4 wk][64 q]
    float* RA = Ksf + wq * 2048;
    float* RB = Vsf + wq * 2048;

    float lfull = lacc + __shfl_xor(lacc, 32);   // partner lane holds other 16 rows

    // phase 1: wk1 -> RA, wk3 -> RB, everyone publishes l
    if (lane < 32) Lb[wk * 64 + wq * 32 + l31] = lfull;
    if (wk == 1) {
#pragma unroll
        for (int r = 0; r < 16; r++) {
            int d0 = (r & 3) + 8 * ((r >> 2) & 3) + 4 * hi;
            RA[l31 * 64 + (d0 ^ l31)] = oacc0[r];
            RA[l31 * 64 + ((d0 + 32) ^ l31)] = oacc1[r];
        }
    }
    if (wk == 3) {
#pragma unroll
        for (int r = 0; r < 16; r++) {
            int d0 = (r & 3) + 8 * ((r >> 2) & 3) + 4 * hi;
            RB[l31 * 64 + (d0 ^ l31)] = oacc0[r];
            RB[l31 * 64 + ((d0 + 32) ^ l31)] = oacc1[r];
        }
    }
    __syncthreads();

    float linv = 0.f;
    if (wk == 0) {
        int idx = wq * 32 + l31;
        linv = 1.f / (Lb[idx] + Lb[64 + idx] + Lb[128 + idx] + Lb[192 + idx]);
#pragma unroll
        for (int r = 0; r < 16; r++) {
            int d0 = (r & 3) + 8 * ((r >> 2) & 3) + 4 * hi;
            oacc0[r] += RA[l31 * 64 + (d0 ^ l31)];
            oacc1[r] += RA[l31 * 64 + ((d0 + 32) ^ l31)];
        }
    }
    if (wk == 2) {
#pragma unroll
        for (int r = 0; r < 16; r++) {
            int d0 = (r & 3) + 8 * ((r >> 2) & 3) + 4 * hi;
            oacc0[r] += RB[l31 * 64 + (d0 ^ l31)];
            oacc1[r] += RB[l31 * 64 + ((d0 + 32) ^ l31)];
        }
    }
    __syncthreads();

    // phase 2: wk2 (now holds k-half {2,3}) -> RA
    if (wk == 2) {
#pragma unroll
        for (int r = 0; r < 16; r++) {
            int d0 = (r & 3) + 8 * ((r >> 2) & 3) + 4 * hi;
            RA[l31 * 64 + (d0 ^ l31)] = oacc0[r];
            RA[l31 * 64 + ((d0 + 32) ^ l31)] = oacc1[r];
        }
    }
    __syncthreads();

    if (wk == 0) {
#pragma unroll
        for (int r = 0; r < 16; r++) {
            int d0 = (r & 3) + 8 * ((r >> 2) & 3) + 4 * hi;
            float v0 = (oacc0[r] + RA[l31 * 64 + (d0 ^ l31)]) * linv;
            float v1 = (oacc1[r] + RA[l31 * 64 + ((d0 + 32) ^ l31)]) * linv;
            RA[l31 * 64 + (d0 ^ l31)] = v0;
            RA[l31 * 64 + ((d0 + 32) ^ l31)] = v1;
        }
    }
    __syncthreads();

    // coalesced store: thread t -> q = t>>3 (0..63), 16B chunk c = t&7
    {
        int qq = t >> 3, cc = t & 7;
        const float* R = Ksf + (qq >> 5) * 2048;
        int ql = qq & 31;
        half8 o;
#pragma unroll
        for (int j = 0; j < 8; j++) {
            int d = cc * 8 + j;
            o[j] = (_Float16)R[ql * 64 + (d ^ ql)];
        }
        *(half8*)&Og[(size_t)(b * NQ_ + qt * 64 + qq) * DM + h * DH_ + cc * 8] = o;
    }
}

// ---------------------------------------------------------------------------
// O projection (unchanged)
// ---------------------------------------------------------------------------
__global__ __launch_bounds__(256, 4) void gemm_o(const _Float16* __restrict__ A,
                                                 const _Float16* __restrict__ W,
                                                 const float* __restrict__ bias,
                                                 float* __restrict__ C) {
    __shared__ _Float16 As[64 * 64];   // 8 KB
    __shared__ _Float16 Bs[64 * 64];   // 8 KB

    const int t = threadIdx.x;
    const int w = t >> 6, lane = t & 63;
    const int r16 = lane & 15, quad = lane >> 4;
    const int blk = blockIdx.x;
    const int bm = (blk & 7) * 8 + ((blk >> 3) & 7);   // 0..63
    const int bn = blk >> 6;                            // 0..15
    const int m0 = bm * 64, n0 = bn * 64;
    const int wm = w >> 1, wn = w & 1;

    floatx4 acc[2][2];
#pragma unroll
    for (int i = 0; i < 2; i++)
#pragma unroll
        for (int j = 0; j < 2; j++)
#pragma unroll
            for (int r = 0; r < 4; r++) acc[i][j][r] = 0.f;

    const int ph0 = quad ^ (r16 & 7), ph1 = ph0 ^ 4;

    for (int k0 = 0; k0 < DM; k0 += 64) {
        __syncthreads();
#pragma unroll
        for (int i = 0; i < 2; i++) {
            int P = i * 256 + t;
            int m = P >> 3, c = (P & 7) ^ (m & 7);
            async16(A + (size_t)(m0 + m) * DM + k0 + c * 8, &As[P * 8]);
            async16(W + (size_t)(n0 + m) * DM + k0 + c * 8, &Bs[P * 8]);
        }
        asm volatile("s_waitcnt vmcnt(0)" ::: "memory");
        __syncthreads();

        half8 af[2][2], bf[2][2];
#pragma unroll
        for (int mi = 0; mi < 2; mi++) {
            int m = wm * 32 + mi * 16 + r16;
            af[mi][0] = ((const half8*)As)[m * 8 + ph0];
            af[mi][1] = ((const half8*)As)[m * 8 + ph1];
        }
#pragma unroll
        for (int ni = 0; ni < 2; ni++) {
            int n = wn * 32 + ni * 16 + r16;
            bf[ni][0] = ((const half8*)Bs)[n * 8 + ph0];
            bf[ni][1] = ((const half8*)Bs)[n * 8 + ph1];
        }
#pragma unroll
        for (int kd = 0; kd < 2; kd++)
#pragma unroll
            for (int mi = 0; mi < 2; mi++)
#pragma unroll
                for (int ni = 0; ni < 2; ni++)
                    acc[mi][ni] = __builtin_amdgcn_mfma_f32_16x16x32_f16(
                        af[mi][kd], bf[ni][kd], acc[mi][ni], 0, 0, 0);
    }

#pragma unroll
    for (int mi = 0; mi < 2; mi++)
#pragma unroll
        for (int r = 0; r < 4; r++) {
            int row = m0 + wm * 32 + mi * 16 + quad * 4 + r;
#pragma unroll
            for (int ni = 0; ni < 2; ni++) {
                int col = n0 + wn * 32 + ni * 16 + r16;
                C[(size_t)row * DM + col] = acc[mi][ni][r] + bias[col];
            }
        }
}

// ---------------------------------------------------------------------------
extern "C" void kernel_launch(void* const* d_in, const int* in_sizes, int n_in,
                              void* d_out, int out_size, void* d_ws, size_t ws_size,
                              hipStream_t stream) {
    const float* q  = (const float*)d_in[0];
    const float* kv = (const float*)d_in[1];
    const float* Wq = (const float*)d_in[2];
    const float* bq = (const float*)d_in[3];
    const float* Wk = (const float*)d_in[4];
    const float* bk = (const float*)d_in[5];
    const float* Wv = (const float*)d_in[6];
    const float* bv = (const float*)d_in[7];
    const float* Wo = (const float*)d_in[8];
    const float* bo = (const float*)d_in[9];

    char* ws = (char*)d_ws;
    _Float16* q16  = (_Float16*)(ws);
    _Float16* kv16 = (_Float16*)(ws + (size_t)(8  << 20));
    _Float16* w16q = (_Float16*)(ws + (size_t)(16 << 20));
    _Float16* w16k = (_Float16*)(ws + (size_t)(18 << 20));
    _Float16* w16v = (_Float16*)(ws + (size_t)(20 << 20));
    _Float16* w16o = (_Float16*)(ws + (size_t)(22 << 20));
    _Float16* qh16 = (_Float16*)(ws + (size_t)(24 << 20));
    _Float16* kh16 = (_Float16*)(ws + (size_t)(32 << 20));
    _Float16* vt16 = (_Float16*)(ws + (size_t)(40 << 20));
    _Float16* ao16 = (_Float16*)(ws + (size_t)(48 << 20));

    cvt_all<<<6144, 256, 0, stream>>>(q, kv, Wq, Wk, Wv, Wo,
                                      q16, kv16, w16q, w16k, w16v, w16o);

    proj_qkv<<<768, 256, 0, stream>>>(q16, kv16, w16q, w16k, w16v,
                                      bq, bk, bv, qh16, kh16, vt16);

    attn_mfma<<<1024, 512, 0, stream>>>(qh16, kh16, vt16, ao16);

    gemm_o<<<1024, 256, 0, stream>>>(ao16, w16o, bo, (float*)d_out);
}

// Round 3
// 203.889 us; speedup vs baseline: 1.9441x; 1.9441x over previous
//
#include <hip/hip_runtime.h>
#include <cstddef>
#include <cstdint>

using half4v  = __attribute__((ext_vector_type(4))) _Float16;
using half8   = __attribute__((ext_vector_type(8))) _Float16;
using floatx4 = __attribute__((ext_vector_type(4))) float;

#define B_   2
#define NQ_  2048
#define DM   1024
#define NH_  16
#define DH_  64
#define NTILES 32   // NKV / 64

// async global->LDS, 16B per lane. LDS dest = wave-uniform base + lane*16.
__device__ __forceinline__ void async16(const _Float16* g, _Float16* l) {
    __builtin_amdgcn_global_load_lds(
        (const __attribute__((address_space(1))) unsigned int*)g,
        (__attribute__((address_space(3))) unsigned int*)l, 16, 0, 0);
}

// ---------------------------------------------------------------------------
// Fused fp32 -> fp16 convert for all 6 tensors (1 launch).
// ---------------------------------------------------------------------------
__global__ __launch_bounds__(256) void cvt_all(
        const float* __restrict__ q,  const float* __restrict__ kv,
        const float* __restrict__ wq, const float* __restrict__ wk,
        const float* __restrict__ wv, const float* __restrict__ wo,
        _Float16* __restrict__ dq,  _Float16* __restrict__ dkv,
        _Float16* __restrict__ dwq, _Float16* __restrict__ dwk,
        _Float16* __restrict__ dwv, _Float16* __restrict__ dwo) {
    int blk = blockIdx.x;
    const float* s;
    _Float16* d;
    int base;
    if (blk < 2048)      { s = q;  d = dq;  base = blk; }
    else if (blk < 4096) { s = kv; d = dkv; base = blk - 2048; }
    else if (blk < 4608) { s = wq; d = dwq; base = blk - 4096; }
    else if (blk < 5120) { s = wk; d = dwk; base = blk - 4608; }
    else if (blk < 5632) { s = wv; d = dwv; base = blk - 5120; }
    else                 { s = wo; d = dwo; base = blk - 5632; }
    int i = base * 256 + threadIdx.x;
    const float4* s4 = (const float4*)s;
    float4 a = s4[2 * i], b = s4[2 * i + 1];
    half8 h;
    h[0] = (_Float16)a.x; h[1] = (_Float16)a.y; h[2] = (_Float16)a.z; h[3] = (_Float16)a.w;
    h[4] = (_Float16)b.x; h[5] = (_Float16)b.y; h[6] = (_Float16)b.z; h[7] = (_Float16)b.w;
    ((half8*)d)[i] = h;
}

// ---------------------------------------------------------------------------
// Fused QKV projection GEMM, 768 blocks (3/CU resident). (unchanged)
// ---------------------------------------------------------------------------
__global__ __launch_bounds__(256, 3) void proj_qkv(
        const _Float16* __restrict__ q16, const _Float16* __restrict__ kv16,
        const _Float16* __restrict__ wqp, const _Float16* __restrict__ wkp,
        const _Float16* __restrict__ wvp,
        const float* __restrict__ bqp, const float* __restrict__ bkp,
        const float* __restrict__ bvp,
        _Float16* __restrict__ qh, _Float16* __restrict__ kh,
        _Float16* __restrict__ vt) {
    __shared__ _Float16 As[128 * 64];   // 16 KB
    __shared__ _Float16 Bs[128 * 64];   // 16 KB

    const int which = blockIdx.x >> 8;
    const int sub = blockIdx.x & 255;
    const _Float16* A = (which == 0) ? q16 : kv16;
    const _Float16* W = (which == 0) ? wqp : (which == 1) ? wkp : wvp;
    const float* bias = (which == 0) ? bqp : (which == 1) ? bkp : bvp;

    const int t = threadIdx.x;
    const int w = t >> 6, lane = t & 63;
    const int r16 = lane & 15, quad = lane >> 4;
    const int bm = (sub & 7) * 4 + ((sub >> 3) & 3);
    const int bn = sub >> 5;
    const int m0 = bm * 128, n0 = bn * 128;
    const int wm = w >> 1, wn = w & 1;

    floatx4 acc[4][4];
#pragma unroll
    for (int i = 0; i < 4; i++)
#pragma unroll
        for (int j = 0; j < 4; j++)
#pragma unroll
            for (int r = 0; r < 4; r++) acc[i][j][r] = 0.f;

    const int ph0 = quad ^ (r16 & 7), ph1 = ph0 ^ 4;

    for (int k0 = 0; k0 < DM; k0 += 64) {
        __syncthreads();
#pragma unroll
        for (int i = 0; i < 4; i++) {
            int P = i * 256 + t;
            int m = P >> 3, c = (P & 7) ^ (m & 7);
            async16(A + (size_t)(m0 + m) * DM + k0 + c * 8, &As[P * 8]);
            async16(W + (size_t)(n0 + m) * DM + k0 + c * 8, &Bs[P * 8]);
        }
        asm volatile("s_waitcnt vmcnt(0)" ::: "memory");
        __syncthreads();

        half8 af[4][2], bf[4][2];
#pragma unroll
        for (int mi = 0; mi < 4; mi++) {
            int m = wm * 64 + mi * 16 + r16;
            af[mi][0] = ((const half8*)As)[m * 8 + ph0];
            af[mi][1] = ((const half8*)As)[m * 8 + ph1];
        }
#pragma unroll
        for (int ni = 0; ni < 4; ni++) {
            int n = wn * 64 + ni * 16 + r16;
            bf[ni][0] = ((const half8*)Bs)[n * 8 + ph0];
            bf[ni][1] = ((const half8*)Bs)[n * 8 + ph1];
        }
#pragma unroll
        for (int kd = 0; kd < 2; kd++)
#pragma unroll
            for (int mi = 0; mi < 4; mi++)
#pragma unroll
                for (int ni = 0; ni < 4; ni++)
                    acc[mi][ni] = __builtin_amdgcn_mfma_f32_16x16x32_f16(
                        af[mi][kd], bf[ni][kd], acc[mi][ni], 0, 0, 0);
    }

    if (which < 2) {
        _Float16* C = (which == 0) ? qh : kh;
        const float esc = (which == 0) ? 0.125f : 1.0f;
#pragma unroll
        for (int mi = 0; mi < 4; mi++)
#pragma unroll
            for (int r = 0; r < 4; r++) {
                int row = m0 + wm * 64 + mi * 16 + quad * 4 + r;
#pragma unroll
                for (int ni = 0; ni < 4; ni++) {
                    int col = n0 + wn * 64 + ni * 16 + r16;
                    C[(size_t)row * DM + col] = (_Float16)((acc[mi][ni][r] + bias[col]) * esc);
                }
            }
    } else {
#pragma unroll
        for (int mi = 0; mi < 4; mi++) {
            int krow = m0 + wm * 64 + mi * 16 + quad * 4;
            int bb = krow >> 11, kk = krow & 2047;
#pragma unroll
            for (int ni = 0; ni < 4; ni++) {
                int col = n0 + wn * 64 + ni * 16 + r16;
                int hh = col >> 6, dd = col & 63;
                float bv = bias[col];
                half4v pk;
#pragma unroll
                for (int r = 0; r < 4; r++) pk[r] = (_Float16)(acc[mi][ni][r] + bv);
                *(half4v*)&vt[((size_t)((bb * NH_ + hh) * DH_ + dd)) * NQ_ + kk] = pk;
            }
        }
    }
}

// ---------------------------------------------------------------------------
// Flash attention, fixed-max softmax. R3: occupancy via kv-split x2.
// R1 lesson: LDS-BW cut neutral. R2 lesson: VGPR cap 64 -> spill disaster.
// Grid 1024 = 4 blocks/CU available; with 4-wave blocks the grid caps the CU
// at 16 waves -> kv-split across waves is the only occupancy lever.
// Block = 512 thr (8 waves = 4 wq x 2 wk). Wave = 16q x 32k, same 16x16 MFMA
// dataflow + swizzles as the verified R0 kernel (one fewer nk level).
// VGPR budget: oaccT 16 + Qf 8 + sacc 8 + transients ~= 70 -> bounds (512,6)
// cap 84: cannot spill. Residency min(grid 4, LDS 4, VGPR 3) = 3 blocks/CU
// = 24 waves/CU (was 16).
// kv-split merge (additive under fixed-max softmax): wk1 publishes O^T f32
// into 16KB region (Ks, XOR-swizzled), l into Ps; wk0 adds + normalizes.
// LDS: Ps 8KB (Q stage -> P buffer) + Ks dbuf 16KB + Vs dbuf 16KB = 40KB.
// ---------------------------------------------------------------------------
__global__ __launch_bounds__(512, 6) void attn_mfma(const _Float16* __restrict__ Qg,
                                                    const _Float16* __restrict__ Kg,
                                                    const _Float16* __restrict__ Vt,
                                                    _Float16* __restrict__ Og) {
    __shared__ _Float16 Ps[64 * 64];     //  8 KB
    __shared__ _Float16 Ks[2][64 * 64];  // 16 KB
    __shared__ _Float16 Vs[2][64 * 64];  // 16 KB

    const int t = threadIdx.x, w = t >> 6, lane = t & 63;
    const int r16 = lane & 15, quad = lane >> 4;
    const int wq = w >> 1, wk = w & 1;   // wave: q rows [wq*16..+16), k cols [wk*32..+32)
    const int blk = blockIdx.x;
    const int bh = (blk & 7) * 4 + ((blk >> 3) & 3);
    const int qt = blk >> 5;                      // 0..31
    const int b = bh >> 4, h = bh & 15;

    const _Float16* qbase = Qg + (size_t)(b * NQ_ + qt * 64) * DM + h * DH_;
    const _Float16* kbase = Kg + (size_t)(b * NQ_) * DM + h * DH_;
    const _Float16* vbase = Vt + (size_t)bh * DH_ * NQ_;

    // prologue: 512 threads stage Q + K0 + V0 (8KB each, one round each)
    {
        int m = t >> 3, c = (t & 7) ^ (m & 7);
        async16(qbase + (size_t)m * DM + c * 8, &Ps[t * 8]);
        async16(kbase + (size_t)m * DM + c * 8, &Ks[0][t * 8]);
        async16(vbase + (size_t)m * NQ_ + c * 8, &Vs[0][t * 8]);
    }
    asm volatile("s_waitcnt vmcnt(0)" ::: "memory");
    __syncthreads();

    const int ph0 = quad ^ (r16 & 7), ph1 = ph0 ^ 4;
    const int q = wq * 16 + r16;        // this lane's q row (S^T col, P row)
    half8 Qf[2];
    Qf[0] = ((const half8*)Ps)[q * 8 + ph0];
    Qf[1] = ((const half8*)Ps)[q * 8 + ph1];
    __syncthreads();   // all Qf reads drained -> Ps reusable as P buffer

    floatx4 oaccT[4];   // O^T partial (wave's 32-k slice): rows d, cols q
    float lacc = 0.f;
#pragma unroll
    for (int nd = 0; nd < 4; nd++)
#pragma unroll
        for (int r = 0; r < 4; r++) oaccT[nd][r] = 0.f;

    for (int kt = 0; kt < NTILES; kt++) {
        const int cur = kt & 1;
        asm volatile("s_waitcnt vmcnt(0)" ::: "memory");  // tile-kt loads landed (own slice)
        __syncthreads();                                  // all waves' slices landed

        if (kt + 1 < NTILES) {   // prefetch tile kt+1 into other buffer
            const int nxt = cur ^ 1;
            int m = t >> 3, c = (t & 7) ^ (m & 7);
            async16(kbase + (size_t)((kt + 1) * 64 + m) * DM + c * 8, &Ks[nxt][t * 8]);
            async16(vbase + (size_t)m * NQ_ + (kt + 1) * 64 + c * 8, &Vs[nxt][t * 8]);
        }

        // S^T[32k x 16q] = K(slice) . Q^T : rows k = wk*32 + nk2*16 + quad*4 + r
        floatx4 sacc[2];
#pragma unroll
        for (int nk2 = 0; nk2 < 2; nk2++)
#pragma unroll
            for (int r = 0; r < 4; r++) sacc[nk2][r] = 0.f;
#pragma unroll
        for (int kd = 0; kd < 2; kd++)
#pragma unroll
            for (int nk2 = 0; nk2 < 2; nk2++) {
                half8 kf = ((const half8*)Ks[cur])[(wk * 32 + nk2 * 16 + r16) * 8 + (kd ? ph1 : ph0)];
                sacc[nk2] = __builtin_amdgcn_mfma_f32_16x16x32_f16(kf, Qf[kd], sacc[nk2], 0, 0, 0);
            }

        // p = exp(s); packed b64 store into wave-private 16q x 32k slice of Ps
#pragma unroll
        for (int nk2 = 0; nk2 < 2; nk2++) {
            float p0 = __expf(sacc[nk2][0]);
            float p1 = __expf(sacc[nk2][1]);
            float p2 = __expf(sacc[nk2][2]);
            float p3 = __expf(sacc[nk2][3]);
            lacc += (p0 + p1) + (p2 + p3);
            half4v pk;
            pk[0] = (_Float16)p0; pk[1] = (_Float16)p1;
            pk[2] = (_Float16)p2; pk[3] = (_Float16)p3;
            int chunk = wk * 4 + nk2 * 2 + (quad >> 1);
            *(half4v*)&Ps[q * 64 + (chunk ^ (r16 & 7)) * 8 + (quad & 1) * 4] = pk;
        }

        // O^T += V^T[:, wave's 32k] . P^T  (P written+read by same wave)
        half8 pf = ((const half8*)Ps)[q * 8 + ((wk * 4 + quad) ^ (r16 & 7))];
#pragma unroll
        for (int nd = 0; nd < 4; nd++) {
            half8 vf = ((const half8*)Vs[cur])[(nd * 16 + r16) * 8 + ((wk * 4 + quad) ^ (r16 & 7))];
            oaccT[nd] = __builtin_amdgcn_mfma_f32_16x16x32_f16(vf, pf, oaccT[nd], 0, 0, 0);
        }
    }

    // ---- epilogue: reduce l over quads, merge wk pair (additive), store.
    lacc += __shfl_xor(lacc, 16);
    lacc += __shfl_xor(lacc, 32);
    __syncthreads();   // all tile-loop LDS reads done; Ks/Ps reusable as scratch

    float* Rg = (float*)Ks;   // 4096 floats: 4 regions [16 q][64 d], XOR-swizzled
    float* Lb = (float*)Ps;   // 128 floats: [2 wk][64 q]
    if (quad == 0) Lb[wk * 64 + q] = lacc;
    if (wk == 1) {
        float* R = Rg + wq * 1024;
#pragma unroll
        for (int nd = 0; nd < 4; nd++)
#pragma unroll
            for (int r = 0; r < 4; r++) {
                int d = nd * 16 + quad * 4 + r;
                R[r16 * 64 + (d ^ (r16 << 2))] = oaccT[nd][r];
            }
    }
    __syncthreads();

    if (wk == 0) {
        float linv = 1.f / (Lb[q] + Lb[64 + q]);
        const float* R = Rg + wq * 1024;
        int qrow = b * NQ_ + qt * 64 + q;
#pragma unroll
        for (int nd = 0; nd < 4; nd++) {
            half4v o;
#pragma unroll
            for (int r = 0; r < 4; r++) {
                int d = nd * 16 + quad * 4 + r;
                float v = oaccT[nd][r] + R[r16 * 64 + (d ^ (r16 << 2))];
                o[r] = (_Float16)(v * linv);
            }
            *(half4v*)&Og[(size_t)qrow * DM + h * DH_ + nd * 16 + quad * 4] = o;
        }
    }
}

// ---------------------------------------------------------------------------
// O projection (unchanged)
// ---------------------------------------------------------------------------
__global__ __launch_bounds__(256, 4) void gemm_o(const _Float16* __restrict__ A,
                                                 const _Float16* __restrict__ W,
                                                 const float* __restrict__ bias,
                                                 float* __restrict__ C) {
    __shared__ _Float16 As[64 * 64];   // 8 KB
    __shared__ _Float16 Bs[64 * 64];   // 8 KB

    const int t = threadIdx.x;
    const int w = t >> 6, lane = t & 63;
    const int r16 = lane & 15, quad = lane >> 4;
    const int blk = blockIdx.x;
    const int bm = (blk & 7) * 8 + ((blk >> 3) & 7);   // 0..63
    const int bn = blk >> 6;                            // 0..15
    const int m0 = bm * 64, n0 = bn * 64;
    const int wm = w >> 1, wn = w & 1;

    floatx4 acc[2][2];
#pragma unroll
    for (int i = 0; i < 2; i++)
#pragma unroll
        for (int j = 0; j < 2; j++)
#pragma unroll
            for (int r = 0; r < 4; r++) acc[i][j][r] = 0.f;

    const int ph0 = quad ^ (r16 & 7), ph1 = ph0 ^ 4;

    for (int k0 = 0; k0 < DM; k0 += 64) {
        __syncthreads();
#pragma unroll
        for (int i = 0; i < 2; i++) {
            int P = i * 256 + t;
            int m = P >> 3, c = (P & 7) ^ (m & 7);
            async16(A + (size_t)(m0 + m) * DM + k0 + c * 8, &As[P * 8]);
            async16(W + (size_t)(n0 + m) * DM + k0 + c * 8, &Bs[P * 8]);
        }
        asm volatile("s_waitcnt vmcnt(0)" ::: "memory");
        __syncthreads();

        half8 af[2][2], bf[2][2];
#pragma unroll
        for (int mi = 0; mi < 2; mi++) {
            int m = wm * 32 + mi * 16 + r16;
            af[mi][0] = ((const half8*)As)[m * 8 + ph0];
            af[mi][1] = ((const half8*)As)[m * 8 + ph1];
        }
#pragma unroll
        for (int ni = 0; ni < 2; ni++) {
            int n = wn * 32 + ni * 16 + r16;
            bf[ni][0] = ((const half8*)Bs)[n * 8 + ph0];
            bf[ni][1] = ((const half8*)Bs)[n * 8 + ph1];
        }
#pragma unroll
        for (int kd = 0; kd < 2; kd++)
#pragma unroll
            for (int mi = 0; mi < 2; mi++)
#pragma unroll
                for (int ni = 0; ni < 2; ni++)
                    acc[mi][ni] = __builtin_amdgcn_mfma_f32_16x16x32_f16(
                        af[mi][kd], bf[ni][kd], acc[mi][ni], 0, 0, 0);
    }

#pragma unroll
    for (int mi = 0; mi < 2; mi++)
#pragma unroll
        for (int r = 0; r < 4; r++) {
            int row = m0 + wm * 32 + mi * 16 + quad * 4 + r;
#pragma unroll
            for (int ni = 0; ni < 2; ni++) {
                int col = n0 + wn * 32 + ni * 16 + r16;
                C[(size_t)row * DM + col] = acc[mi][ni][r] + bias[col];
            }
        }
}

// ---------------------------------------------------------------------------
extern "C" void kernel_launch(void* const* d_in, const int* in_sizes, int n_in,
                              void* d_out, int out_size, void* d_ws, size_t ws_size,
                              hipStream_t stream) {
    const float* q  = (const float*)d_in[0];
    const float* kv = (const float*)d_in[1];
    const float* Wq = (const float*)d_in[2];
    const float* bq = (const float*)d_in[3];
    const float* Wk = (const float*)d_in[4];
    const float* bk = (const float*)d_in[5];
    const float* Wv = (const float*)d_in[6];
    const float* bv = (const float*)d_in[7];
    const float* Wo = (const float*)d_in[8];
    const float* bo = (const float*)d_in[9];

    char* ws = (char*)d_ws;
    _Float16* q16  = (_Float16*)(ws);
    _Float16* kv16 = (_Float16*)(ws + (size_t)(8  << 20));
    _Float16* w16q = (_Float16*)(ws + (size_t)(16 << 20));
    _Float16* w16k = (_Float16*)(ws + (size_t)(18 << 20));
    _Float16* w16v = (_Float16*)(ws + (size_t)(20 << 20));
    _Float16* w16o = (_Float16*)(ws + (size_t)(22 << 20));
    _Float16* qh16 = (_Float16*)(ws + (size_t)(24 << 20));
    _Float16* kh16 = (_Float16*)(ws + (size_t)(32 << 20));
    _Float16* vt16 = (_Float16*)(ws + (size_t)(40 << 20));
    _Float16* ao16 = (_Float16*)(ws + (size_t)(48 << 20));

    cvt_all<<<6144, 256, 0, stream>>>(q, kv, Wq, Wk, Wv, Wo,
                                      q16, kv16, w16q, w16k, w16v, w16o);

    proj_qkv<<<768, 256, 0, stream>>>(q16, kv16, w16q, w16k, w16v,
                                      bq, bk, bv, qh16, kh16, vt16);

    attn_mfma<<<1024, 512, 0, stream>>>(qh16, kh16, vt16, ao16);

    gemm_o<<<1024, 256, 0, stream>>>(ao16, w16o, bo, (float*)d_out);
}

// Round 4
// 199.573 us; speedup vs baseline: 1.9862x; 1.0216x over previous
//
#include <hip/hip_runtime.h>
#include <cstddef>
#include <cstdint>

using half4v   = __attribute__((ext_vector_type(4))) _Float16;
using half8    = __attribute__((ext_vector_type(8))) _Float16;
using floatx4  = __attribute__((ext_vector_type(4))) float;
using floatx16 = __attribute__((ext_vector_type(16))) float;

#define B_   2
#define NQ_  2048
#define DM   1024
#define NH_  16
#define DH_  64
#define NTILES 32   // NKV / 64

// async global->LDS, 16B per lane. LDS dest = wave-uniform base + lane*16.
__device__ __forceinline__ void async16(const _Float16* g, _Float16* l) {
    __builtin_amdgcn_global_load_lds(
        (const __attribute__((address_space(1))) unsigned int*)g,
        (__attribute__((address_space(3))) unsigned int*)l, 16, 0, 0);
}

// RNE pack 2 f32 -> u32 of 2 f16 (matches baseline numerics).
__device__ __forceinline__ unsigned pkh(float a, float b) {
    union { _Float16 h[2]; unsigned u; } x;
    x.h[0] = (_Float16)a; x.h[1] = (_Float16)b;
    return x.u;
}

// ---------------------------------------------------------------------------
// Fused fp32 -> fp16 convert for all 6 tensors (1 launch).
// ---------------------------------------------------------------------------
__global__ __launch_bounds__(256) void cvt_all(
        const float* __restrict__ q,  const float* __restrict__ kv,
        const float* __restrict__ wq, const float* __restrict__ wk,
        const float* __restrict__ wv, const float* __restrict__ wo,
        _Float16* __restrict__ dq,  _Float16* __restrict__ dkv,
        _Float16* __restrict__ dwq, _Float16* __restrict__ dwk,
        _Float16* __restrict__ dwv, _Float16* __restrict__ dwo) {
    int blk = blockIdx.x;
    const float* s;
    _Float16* d;
    int base;
    if (blk < 2048)      { s = q;  d = dq;  base = blk; }
    else if (blk < 4096) { s = kv; d = dkv; base = blk - 2048; }
    else if (blk < 4608) { s = wq; d = dwq; base = blk - 4096; }
    else if (blk < 5120) { s = wk; d = dwk; base = blk - 4608; }
    else if (blk < 5632) { s = wv; d = dwv; base = blk - 5120; }
    else                 { s = wo; d = dwo; base = blk - 5632; }
    int i = base * 256 + threadIdx.x;
    const float4* s4 = (const float4*)s;
    float4 a = s4[2 * i], b = s4[2 * i + 1];
    half8 h;
    h[0] = (_Float16)a.x; h[1] = (_Float16)a.y; h[2] = (_Float16)a.z; h[3] = (_Float16)a.w;
    h[4] = (_Float16)b.x; h[5] = (_Float16)b.y; h[6] = (_Float16)b.z; h[7] = (_Float16)b.w;
    ((half8*)d)[i] = h;
}

// ---------------------------------------------------------------------------
// Fused QKV projection GEMM, 768 blocks (3/CU resident). (unchanged)
// ---------------------------------------------------------------------------
__global__ __launch_bounds__(256, 3) void proj_qkv(
        const _Float16* __restrict__ q16, const _Float16* __restrict__ kv16,
        const _Float16* __restrict__ wqp, const _Float16* __restrict__ wkp,
        const _Float16* __restrict__ wvp,
        const float* __restrict__ bqp, const float* __restrict__ bkp,
        const float* __restrict__ bvp,
        _Float16* __restrict__ qh, _Float16* __restrict__ kh,
        _Float16* __restrict__ vt) {
    __shared__ _Float16 As[128 * 64];   // 16 KB
    __shared__ _Float16 Bs[128 * 64];   // 16 KB

    const int which = blockIdx.x >> 8;
    const int sub = blockIdx.x & 255;
    const _Float16* A = (which == 0) ? q16 : kv16;
    const _Float16* W = (which == 0) ? wqp : (which == 1) ? wkp : wvp;
    const float* bias = (which == 0) ? bqp : (which == 1) ? bkp : bvp;

    const int t = threadIdx.x;
    const int w = t >> 6, lane = t & 63;
    const int r16 = lane & 15, quad = lane >> 4;
    const int bm = (sub & 7) * 4 + ((sub >> 3) & 3);
    const int bn = sub >> 5;
    const int m0 = bm * 128, n0 = bn * 128;
    const int wm = w >> 1, wn = w & 1;

    floatx4 acc[4][4];
#pragma unroll
    for (int i = 0; i < 4; i++)
#pragma unroll
        for (int j = 0; j < 4; j++)
#pragma unroll
            for (int r = 0; r < 4; r++) acc[i][j][r] = 0.f;

    const int ph0 = quad ^ (r16 & 7), ph1 = ph0 ^ 4;

    for (int k0 = 0; k0 < DM; k0 += 64) {
        __syncthreads();
#pragma unroll
        for (int i = 0; i < 4; i++) {
            int P = i * 256 + t;
            int m = P >> 3, c = (P & 7) ^ (m & 7);
            async16(A + (size_t)(m0 + m) * DM + k0 + c * 8, &As[P * 8]);
            async16(W + (size_t)(n0 + m) * DM + k0 + c * 8, &Bs[P * 8]);
        }
        asm volatile("s_waitcnt vmcnt(0)" ::: "memory");
        __syncthreads();

        half8 af[4][2], bf[4][2];
#pragma unroll
        for (int mi = 0; mi < 4; mi++) {
            int m = wm * 64 + mi * 16 + r16;
            af[mi][0] = ((const half8*)As)[m * 8 + ph0];
            af[mi][1] = ((const half8*)As)[m * 8 + ph1];
        }
#pragma unroll
        for (int ni = 0; ni < 4; ni++) {
            int n = wn * 64 + ni * 16 + r16;
            bf[ni][0] = ((const half8*)Bs)[n * 8 + ph0];
            bf[ni][1] = ((const half8*)Bs)[n * 8 + ph1];
        }
#pragma unroll
        for (int kd = 0; kd < 2; kd++)
#pragma unroll
            for (int mi = 0; mi < 4; mi++)
#pragma unroll
                for (int ni = 0; ni < 4; ni++)
                    acc[mi][ni] = __builtin_amdgcn_mfma_f32_16x16x32_f16(
                        af[mi][kd], bf[ni][kd], acc[mi][ni], 0, 0, 0);
    }

    if (which < 2) {
        _Float16* C = (which == 0) ? qh : kh;
        const float esc = (which == 0) ? 0.125f : 1.0f;
#pragma unroll
        for (int mi = 0; mi < 4; mi++)
#pragma unroll
            for (int r = 0; r < 4; r++) {
                int row = m0 + wm * 64 + mi * 16 + quad * 4 + r;
#pragma unroll
                for (int ni = 0; ni < 4; ni++) {
                    int col = n0 + wn * 64 + ni * 16 + r16;
                    C[(size_t)row * DM + col] = (_Float16)((acc[mi][ni][r] + bias[col]) * esc);
                }
            }
    } else {
#pragma unroll
        for (int mi = 0; mi < 4; mi++) {
            int krow = m0 + wm * 64 + mi * 16 + quad * 4;
            int bb = krow >> 11, kk = krow & 2047;
#pragma unroll
            for (int ni = 0; ni < 4; ni++) {
                int col = n0 + wn * 64 + ni * 16 + r16;
                int hh = col >> 6, dd = col & 63;
                float bv = bias[col];
                half4v pk;
#pragma unroll
                for (int r = 0; r < 4; r++) pk[r] = (_Float16)(acc[mi][ni][r] + bv);
                *(half4v*)&vt[((size_t)((bb * NH_ + hh) * DH_ + dd)) * NQ_ + kk] = pk;
            }
        }
    }
}

// ---------------------------------------------------------------------------
// Flash attention, fixed-max softmax. R4: 32x32 MFMA density restructure.
// Evidence: R1 (LDS-BW cut) neutral, R3 (occupancy 32->63%) neutral, MfmaUtil
// pinned at 22% -> the limiter is MFMA work per overhead quantum (softmax
// chain + barrier cadence per wave-tile), not any pipe's bandwidth.
// R2 validated this dataflow's numerics (passed; died of VGPR-64 spill).
// Block = 256 thr (4 waves). Wave = 32q x 64k per tile, mfma_f32_32x32x16:
// 16 MFMA = 524 kFLOP per wave-tile, 4x R3's 131 kFLOP. Grid 512 = 32bh x
// 16 qtiles (128q). No kv-split -> no merge epilogue; l = lane-sum + 1 shfl.
// P in registers: RNE pack + shfl_xor(32) half-exchange (R2-verified).
// K/V dbuf (prefetch during compute, vmcnt(0)+barrier per tile), Q staged
// once and hoisted to 16 VGPR. setprio(1) around MFMA clusters (T5).
// VGPR ~100 (oacc 32 + qf 16 + sacc 16 + temps) under (256,4) cap 128.
// LDS: Qs 16KB + Ks dbuf 16KB + Vs dbuf 16KB = 48KB (grid-capped 2 blk/CU).
// ---------------------------------------------------------------------------
__global__ __launch_bounds__(256, 4) void attn_mfma(const _Float16* __restrict__ Qg,
                                                    const _Float16* __restrict__ Kg,
                                                    const _Float16* __restrict__ Vt,
                                                    _Float16* __restrict__ Og) {
    __shared__ _Float16 Qs[128 * 64];    // 16 KB: [128 q][64 d], chunk^(q&7)
    __shared__ _Float16 Ks[2][64 * 64];  // 16 KB: [64 k][64 d], chunk^(k&7)
    __shared__ _Float16 Vs[2][64 * 64];  // 16 KB: [64 d][64 k], chunk^(d&7)

    const int t = threadIdx.x, w = t >> 6, lane = t & 63;
    const int l31 = lane & 31, hi = lane >> 5;
    const int blk = blockIdx.x;
    const int bh = (blk & 7) * 4 + ((blk >> 3) & 3);
    const int qt = blk >> 5;                      // 0..15 (128 q rows each)
    const int b = bh >> 4, h = bh & 15;

    const _Float16* qbase = Qg + (size_t)(b * NQ_ + qt * 128) * DM + h * DH_;
    const _Float16* kbase = Kg + (size_t)(b * NQ_) * DM + h * DH_;
    const _Float16* vbase = Vt + (size_t)bh * DH_ * NQ_;

    // prologue: stage Q (128x64, 4 rounds) + K0/V0 (2 rounds each)
#pragma unroll
    for (int r = 0; r < 4; r++) {
        int P = r * 256 + t;
        int m = P >> 3, c = (P & 7) ^ (m & 7);
        async16(qbase + (size_t)m * DM + c * 8, &Qs[P * 8]);
    }
#pragma unroll
    for (int r = 0; r < 2; r++) {
        int P = r * 256 + t;
        int m = P >> 3, c = (P & 7) ^ (m & 7);
        async16(kbase + (size_t)m * DM + c * 8, &Ks[0][P * 8]);
        async16(vbase + (size_t)m * NQ_ + c * 8, &Vs[0][P * 8]);
    }
    asm volatile("s_waitcnt vmcnt(0)" ::: "memory");
    __syncthreads();

    // hoist Q B-frags: col q = w*32 + l31, slice s covers d = s*16 + hi*8 + j
    half8 qf[4];
    {
        int qr = w * 32 + l31;
#pragma unroll
        for (int s = 0; s < 4; s++)
            qf[s] = ((const half8*)Qs)[qr * 8 + ((s * 2 + hi) ^ (qr & 7))];
    }

    floatx16 oacc0, oacc1;   // O^T [64 d][32 q]: d-blocks 0/1
#pragma unroll
    for (int r = 0; r < 16; r++) { oacc0[r] = 0.f; oacc1[r] = 0.f; }
    float lacc = 0.f;

    for (int kt = 0; kt < NTILES; kt++) {
        const int cur = kt & 1;
        asm volatile("s_waitcnt vmcnt(0)" ::: "memory");  // tile-kt loads landed
        __syncthreads();                                  // all waves' slices landed

        if (kt + 1 < NTILES) {   // prefetch tile kt+1 into other buffer
            const int nxt = cur ^ 1;
#pragma unroll
            for (int r = 0; r < 2; r++) {
                int P = r * 256 + t;
                int m = P >> 3, c = (P & 7) ^ (m & 7);
                async16(kbase + (size_t)((kt + 1) * 64 + m) * DM + c * 8, &Ks[nxt][P * 8]);
                async16(vbase + (size_t)m * NQ_ + (kt + 1) * 64 + c * 8, &Vs[nxt][P * 8]);
            }
        }

#pragma unroll
        for (int kh2 = 0; kh2 < 2; kh2++) {
            // S^T[32k x 32q] = K(half) . Q^T : A rows k = kh2*32+l31 slice-k d
            floatx16 sacc;
#pragma unroll
            for (int r = 0; r < 16; r++) sacc[r] = 0.f;
            __builtin_amdgcn_s_setprio(1);
#pragma unroll
            for (int s = 0; s < 4; s++) {
                half8 kf = ((const half8*)Ks[cur])[(kh2 * 32 + l31) * 8 + ((s * 2 + hi) ^ (l31 & 7))];
                sacc = __builtin_amdgcn_mfma_f32_32x32x16_f16(kf, qf[s], sacc, 0, 0, 0);
            }
            __builtin_amdgcn_s_setprio(0);

            // softmax (fixed max): exp in place, accumulate l
#pragma unroll
            for (int r = 0; r < 16; r++) sacc[r] = __expf(sacc[r]);
#pragma unroll
            for (int r = 0; r < 16; r++) lacc += sacc[r];

            // P -> PV B-frags in registers (R2-verified exchange).
            half8 pf0, pf1;
            {
                unsigned a0 = pkh(sacc[0], sacc[1]),  a1 = pkh(sacc[2], sacc[3]);
                unsigned b0 = pkh(sacc[4], sacc[5]),  b1 = pkh(sacc[6], sacc[7]);
                unsigned s0 = hi ? a0 : b0, s1 = hi ? a1 : b1;
                unsigned r0 = (unsigned)__shfl_xor((int)s0, 32);
                unsigned r1 = (unsigned)__shfl_xor((int)s1, 32);
                union { unsigned u[4]; half8 hh; } pu;
                pu.u[0] = hi ? r0 : a0; pu.u[1] = hi ? r1 : a1;
                pu.u[2] = hi ? b0 : r0; pu.u[3] = hi ? b1 : r1;
                pf0 = pu.hh;
            }
            {
                unsigned a0 = pkh(sacc[8], sacc[9]),   a1 = pkh(sacc[10], sacc[11]);
                unsigned b0 = pkh(sacc[12], sacc[13]), b1 = pkh(sacc[14], sacc[15]);
                unsigned s0 = hi ? a0 : b0, s1 = hi ? a1 : b1;
                unsigned r0 = (unsigned)__shfl_xor((int)s0, 32);
                unsigned r1 = (unsigned)__shfl_xor((int)s1, 32);
                union { unsigned u[4]; half8 hh; } pu;
                pu.u[0] = hi ? r0 : a0; pu.u[1] = hi ? r1 : a1;
                pu.u[2] = hi ? b0 : r0; pu.u[3] = hi ? b1 : r1;
                pf1 = pu.hh;
            }

            // O^T += V^T[:, kh2-half] . P^T
            __builtin_amdgcn_s_setprio(1);
#pragma unroll
            for (int s2 = 0; s2 < 2; s2++) {
                half8 pfk = s2 ? pf1 : pf0;
                {
                    half8 vf = ((const half8*)Vs[cur])[(0 * 32 + l31) * 8 + ((kh2 * 4 + s2 * 2 + hi) ^ (l31 & 7))];
                    oacc0 = __builtin_amdgcn_mfma_f32_32x32x16_f16(vf, pfk, oacc0, 0, 0, 0);
                }
                {
                    half8 vf = ((const half8*)Vs[cur])[(1 * 32 + l31) * 8 + ((kh2 * 4 + s2 * 2 + hi) ^ (l31 & 7))];
                    oacc1 = __builtin_amdgcn_mfma_f32_32x32x16_f16(vf, pfk, oacc1, 0, 0, 0);
                }
            }
            __builtin_amdgcn_s_setprio(0);
        }
    }

    // epilogue: l = own 32 rows + partner's 32 (lane^32), normalize, store.
    // C layout: col q = l31, row d = dblk*32 + (r&3) + 8*(r>>2) + 4*hi.
    {
        float lt = lacc + __shfl_xor(lacc, 32);
        float linv = 1.f / lt;
        int qrow = b * NQ_ + qt * 128 + w * 32 + l31;
#pragma unroll
        for (int g = 0; g < 4; g++) {
            half4v o0, o1;
#pragma unroll
            for (int j = 0; j < 4; j++) {
                o0[j] = (_Float16)(oacc0[g * 4 + j] * linv);
                o1[j] = (_Float16)(oacc1[g * 4 + j] * linv);
            }
            int d0 = g * 8 + 4 * hi;
            *(half4v*)&Og[(size_t)qrow * DM + h * DH_ + d0] = o0;
            *(half4v*)&Og[(size_t)qrow * DM + h * DH_ + 32 + d0] = o1;
        }
    }
}

// ---------------------------------------------------------------------------
// O projection (unchanged)
// ---------------------------------------------------------------------------
__global__ __launch_bounds__(256, 4) void gemm_o(const _Float16* __restrict__ A,
                                                 const _Float16* __restrict__ W,
                                                 const float* __restrict__ bias,
                                                 float* __restrict__ C) {
    __shared__ _Float16 As[64 * 64];   // 8 KB
    __shared__ _Float16 Bs[64 * 64];   // 8 KB

    const int t = threadIdx.x;
    const int w = t >> 6, lane = t & 63;
    const int r16 = lane & 15, quad = lane >> 4;
    const int blk = blockIdx.x;
    const int bm = (blk & 7) * 8 + ((blk >> 3) & 7);   // 0..63
    const int bn = blk >> 6;                            // 0..15
    const int m0 = bm * 64, n0 = bn * 64;
    const int wm = w >> 1, wn = w & 1;

    floatx4 acc[2][2];
#pragma unroll
    for (int i = 0; i < 2; i++)
#pragma unroll
        for (int j = 0; j < 2; j++)
#pragma unroll
            for (int r = 0; r < 4; r++) acc[i][j][r] = 0.f;

    const int ph0 = quad ^ (r16 & 7), ph1 = ph0 ^ 4;

    for (int k0 = 0; k0 < DM; k0 += 64) {
        __syncthreads();
#pragma unroll
        for (int i = 0; i < 2; i++) {
            int P = i * 256 + t;
            int m = P >> 3, c = (P & 7) ^ (m & 7);
            async16(A + (size_t)(m0 + m) * DM + k0 + c * 8, &As[P * 8]);
            async16(W + (size_t)(n0 + m) * DM + k0 + c * 8, &Bs[P * 8]);
        }
        asm volatile("s_waitcnt vmcnt(0)" ::: "memory");
        __syncthreads();

        half8 af[2][2], bf[2][2];
#pragma unroll
        for (int mi = 0; mi < 2; mi++) {
            int m = wm * 32 + mi * 16 + r16;
            af[mi][0] = ((const half8*)As)[m * 8 + ph0];
            af[mi][1] = ((const half8*)As)[m * 8 + ph1];
        }
#pragma unroll
        for (int ni = 0; ni < 2; ni++) {
            int n = wn * 32 + ni * 16 + r16;
            bf[ni][0] = ((const half8*)Bs)[n * 8 + ph0];
            bf[ni][1] = ((const half8*)Bs)[n * 8 + ph1];
        }
#pragma unroll
        for (int kd = 0; kd < 2; kd++)
#pragma unroll
            for (int mi = 0; mi < 2; mi++)
#pragma unroll
                for (int ni = 0; ni < 2; ni++)
                    acc[mi][ni] = __builtin_amdgcn_mfma_f32_16x16x32_f16(
                        af[mi][kd], bf[ni][kd], acc[mi][ni], 0, 0, 0);
    }

#pragma unroll
    for (int mi = 0; mi < 2; mi++)
#pragma unroll
        for (int r = 0; r < 4; r++) {
            int row = m0 + wm * 32 + mi * 16 + quad * 4 + r;
#pragma unroll
            for (int ni = 0; ni < 2; ni++) {
                int col = n0 + wn * 32 + ni * 16 + r16;
                C[(size_t)row * DM + col] = acc[mi][ni][r] + bias[col];
            }
        }
}

// ---------------------------------------------------------------------------
extern "C" void kernel_launch(void* const* d_in, const int* in_sizes, int n_in,
                              void* d_out, int out_size, void* d_ws, size_t ws_size,
                              hipStream_t stream) {
    const float* q  = (const float*)d_in[0];
    const float* kv = (const float*)d_in[1];
    const float* Wq = (const float*)d_in[2];
    const float* bq = (const float*)d_in[3];
    const float* Wk = (const float*)d_in[4];
    const float* bk = (const float*)d_in[5];
    const float* Wv = (const float*)d_in[6];
    const float* bv = (const float*)d_in[7];
    const float* Wo = (const float*)d_in[8];
    const float* bo = (const float*)d_in[9];

    char* ws = (char*)d_ws;
    _Float16* q16  = (_Float16*)(ws);
    _Float16* kv16 = (_Float16*)(ws + (size_t)(8  << 20));
    _Float16* w16q = (_Float16*)(ws + (size_t)(16 << 20));
    _Float16* w16k = (_Float16*)(ws + (size_t)(18 << 20));
    _Float16* w16v = (_Float16*)(ws + (size_t)(20 << 20));
    _Float16* w16o = (_Float16*)(ws + (size_t)(22 << 20));
    _Float16* qh16 = (_Float16*)(ws + (size_t)(24 << 20));
    _Float16* kh16 = (_Float16*)(ws + (size_t)(32 << 20));
    _Float16* vt16 = (_Float16*)(ws + (size_t)(40 << 20));
    _Float16* ao16 = (_Float16*)(ws + (size_t)(48 << 20));

    cvt_all<<<6144, 256, 0, stream>>>(q, kv, Wq, Wk, Wv, Wo,
                                      q16, kv16, w16q, w16k, w16v, w16o);

    proj_qkv<<<768, 256, 0, stream>>>(q16, kv16, w16q, w16k, w16v,
                                      bq, bk, bv, qh16, kh16, vt16);

    attn_mfma<<<512, 256, 0, stream>>>(qh16, kh16, vt16, ao16);

    gemm_o<<<1024, 256, 0, stream>>>(ao16, w16o, bo, (float*)d_out);
}

// Round 5
// 197.980 us; speedup vs baseline: 2.0022x; 1.0080x over previous
//
#include <hip/hip_runtime.h>
#include <cstddef>
#include <cstdint>

using half4v   = __attribute__((ext_vector_type(4))) _Float16;
using half8    = __attribute__((ext_vector_type(8))) _Float16;
using floatx4  = __attribute__((ext_vector_type(4))) float;
using floatx16 = __attribute__((ext_vector_type(16))) float;

#define B_   2
#define NQ_  2048
#define DM   1024
#define NH_  16
#define DH_  64
#define NTILES 32   // NKV / 64

// async global->LDS, 16B per lane. LDS dest = wave-uniform base + lane*16.
__device__ __forceinline__ void async16(const _Float16* g, _Float16* l) {
    __builtin_amdgcn_global_load_lds(
        (const __attribute__((address_space(1))) unsigned int*)g,
        (__attribute__((address_space(3))) unsigned int*)l, 16, 0, 0);
}

// RNE pack 2 f32 -> u32 of 2 f16 (matches baseline numerics).
__device__ __forceinline__ unsigned pkh(float a, float b) {
    union { _Float16 h[2]; unsigned u; } x;
    x.h[0] = (_Float16)a; x.h[1] = (_Float16)b;
    return x.u;
}

// ---------------------------------------------------------------------------
// Fused fp32 -> fp16 convert for all 6 tensors (1 launch).
// ---------------------------------------------------------------------------
__global__ __launch_bounds__(256) void cvt_all(
        const float* __restrict__ q,  const float* __restrict__ kv,
        const float* __restrict__ wq, const float* __restrict__ wk,
        const float* __restrict__ wv, const float* __restrict__ wo,
        _Float16* __restrict__ dq,  _Float16* __restrict__ dkv,
        _Float16* __restrict__ dwq, _Float16* __restrict__ dwk,
        _Float16* __restrict__ dwv, _Float16* __restrict__ dwo) {
    int blk = blockIdx.x;
    const float* s;
    _Float16* d;
    int base;
    if (blk < 2048)      { s = q;  d = dq;  base = blk; }
    else if (blk < 4096) { s = kv; d = dkv; base = blk - 2048; }
    else if (blk < 4608) { s = wq; d = dwq; base = blk - 4096; }
    else if (blk < 5120) { s = wk; d = dwk; base = blk - 4608; }
    else if (blk < 5632) { s = wv; d = dwv; base = blk - 5120; }
    else                 { s = wo; d = dwo; base = blk - 5632; }
    int i = base * 256 + threadIdx.x;
    const float4* s4 = (const float4*)s;
    float4 a = s4[2 * i], b = s4[2 * i + 1];
    half8 h;
    h[0] = (_Float16)a.x; h[1] = (_Float16)a.y; h[2] = (_Float16)a.z; h[3] = (_Float16)a.w;
    h[4] = (_Float16)b.x; h[5] = (_Float16)b.y; h[6] = (_Float16)b.z; h[7] = (_Float16)b.w;
    ((half8*)d)[i] = h;
}

// ---------------------------------------------------------------------------
// Fused QKV projection GEMM, 768 blocks (3/CU resident).
// R5: Q scale now 0.125*log2(e) so attn softmax uses bare exp2 (v_exp_f32
// without the leading v_mul). Numerically identical up to f16 rounding spot.
// ---------------------------------------------------------------------------
__global__ __launch_bounds__(256, 3) void proj_qkv(
        const _Float16* __restrict__ q16, const _Float16* __restrict__ kv16,
        const _Float16* __restrict__ wqp, const _Float16* __restrict__ wkp,
        const _Float16* __restrict__ wvp,
        const float* __restrict__ bqp, const float* __restrict__ bkp,
        const float* __restrict__ bvp,
        _Float16* __restrict__ qh, _Float16* __restrict__ kh,
        _Float16* __restrict__ vt) {
    __shared__ _Float16 As[128 * 64];   // 16 KB
    __shared__ _Float16 Bs[128 * 64];   // 16 KB

    const int which = blockIdx.x >> 8;
    const int sub = blockIdx.x & 255;
    const _Float16* A = (which == 0) ? q16 : kv16;
    const _Float16* W = (which == 0) ? wqp : (which == 1) ? wkp : wvp;
    const float* bias = (which == 0) ? bqp : (which == 1) ? bkp : bvp;

    const int t = threadIdx.x;
    const int w = t >> 6, lane = t & 63;
    const int r16 = lane & 15, quad = lane >> 4;
    const int bm = (sub & 7) * 4 + ((sub >> 3) & 3);
    const int bn = sub >> 5;
    const int m0 = bm * 128, n0 = bn * 128;
    const int wm = w >> 1, wn = w & 1;

    floatx4 acc[4][4];
#pragma unroll
    for (int i = 0; i < 4; i++)
#pragma unroll
        for (int j = 0; j < 4; j++)
#pragma unroll
            for (int r = 0; r < 4; r++) acc[i][j][r] = 0.f;

    const int ph0 = quad ^ (r16 & 7), ph1 = ph0 ^ 4;

    for (int k0 = 0; k0 < DM; k0 += 64) {
        __syncthreads();
#pragma unroll
        for (int i = 0; i < 4; i++) {
            int P = i * 256 + t;
            int m = P >> 3, c = (P & 7) ^ (m & 7);
            async16(A + (size_t)(m0 + m) * DM + k0 + c * 8, &As[P * 8]);
            async16(W + (size_t)(n0 + m) * DM + k0 + c * 8, &Bs[P * 8]);
        }
        asm volatile("s_waitcnt vmcnt(0)" ::: "memory");
        __syncthreads();

        half8 af[4][2], bf[4][2];
#pragma unroll
        for (int mi = 0; mi < 4; mi++) {
            int m = wm * 64 + mi * 16 + r16;
            af[mi][0] = ((const half8*)As)[m * 8 + ph0];
            af[mi][1] = ((const half8*)As)[m * 8 + ph1];
        }
#pragma unroll
        for (int ni = 0; ni < 4; ni++) {
            int n = wn * 64 + ni * 16 + r16;
            bf[ni][0] = ((const half8*)Bs)[n * 8 + ph0];
            bf[ni][1] = ((const half8*)Bs)[n * 8 + ph1];
        }
#pragma unroll
        for (int kd = 0; kd < 2; kd++)
#pragma unroll
            for (int mi = 0; mi < 4; mi++)
#pragma unroll
                for (int ni = 0; ni < 4; ni++)
                    acc[mi][ni] = __builtin_amdgcn_mfma_f32_16x16x32_f16(
                        af[mi][kd], bf[ni][kd], acc[mi][ni], 0, 0, 0);
    }

    if (which < 2) {
        _Float16* C = (which == 0) ? qh : kh;
        // 0.125 * log2(e): softmax downstream uses exp2 directly.
        const float esc = (which == 0) ? 0.18033688011112042f : 1.0f;
#pragma unroll
        for (int mi = 0; mi < 4; mi++)
#pragma unroll
            for (int r = 0; r < 4; r++) {
                int row = m0 + wm * 64 + mi * 16 + quad * 4 + r;
#pragma unroll
                for (int ni = 0; ni < 4; ni++) {
                    int col = n0 + wn * 64 + ni * 16 + r16;
                    C[(size_t)row * DM + col] = (_Float16)((acc[mi][ni][r] + bias[col]) * esc);
                }
            }
    } else {
#pragma unroll
        for (int mi = 0; mi < 4; mi++) {
            int krow = m0 + wm * 64 + mi * 16 + quad * 4;
            int bb = krow >> 11, kk = krow & 2047;
#pragma unroll
            for (int ni = 0; ni < 4; ni++) {
                int col = n0 + wn * 64 + ni * 16 + r16;
                int hh = col >> 6, dd = col & 63;
                float bv = bias[col];
                half4v pk;
#pragma unroll
                for (int r = 0; r < 4; r++) pk[r] = (_Float16)(acc[mi][ni][r] + bv);
                *(half4v*)&vt[((size_t)((bb * NH_ + hh) * DH_ + dd)) * NQ_ + kk] = pk;
            }
        }
    }
}

// ---------------------------------------------------------------------------
// Flash attention, fixed-max softmax. R5: serial-chain VALU/cross-lane cut.
// Evidence R0-R4: time glued at 63us across 4 structures; MfmaUtil ~23 +
// VALUBusy 57 = 80% combined busy -> issue-dominated, not BW/occupancy.
// Two chain poisons removed this round:
//  1. __shfl_xor(,32) (= ds_bpermute, LDS pipe + lgkm wait, 4x per tile in
//     the S->P->PV chain) -> v_permlane32_swap_b32 (pure VALU, 1 instr per
//     register pair, T12/m255: 1.20x vs bpermute).
//  2. __expf (v_mul + v_exp) -> bare exp2 (log2e folded into Q projection).
// Geometry unchanged from R4 (proven numerics): 4 waves, 32q x 64k per wave,
// 32x32x16 MFMA, P in registers, K/V dbuf, grid 512.
// ---------------------------------------------------------------------------
__global__ __launch_bounds__(256, 4) void attn_mfma(const _Float16* __restrict__ Qg,
                                                    const _Float16* __restrict__ Kg,
                                                    const _Float16* __restrict__ Vt,
                                                    _Float16* __restrict__ Og) {
    __shared__ _Float16 Qs[128 * 64];    // 16 KB: [128 q][64 d], chunk^(q&7)
    __shared__ _Float16 Ks[2][64 * 64];  // 16 KB: [64 k][64 d], chunk^(k&7)
    __shared__ _Float16 Vs[2][64 * 64];  // 16 KB: [64 d][64 k], chunk^(d&7)

    const int t = threadIdx.x, w = t >> 6, lane = t & 63;
    const int l31 = lane & 31, hi = lane >> 5;
    const int blk = blockIdx.x;
    const int bh = (blk & 7) * 4 + ((blk >> 3) & 3);
    const int qt = blk >> 5;                      // 0..15 (128 q rows each)
    const int b = bh >> 4, h = bh & 15;

    const _Float16* qbase = Qg + (size_t)(b * NQ_ + qt * 128) * DM + h * DH_;
    const _Float16* kbase = Kg + (size_t)(b * NQ_) * DM + h * DH_;
    const _Float16* vbase = Vt + (size_t)bh * DH_ * NQ_;

    // prologue: stage Q (128x64, 4 rounds) + K0/V0 (2 rounds each)
#pragma unroll
    for (int r = 0; r < 4; r++) {
        int P = r * 256 + t;
        int m = P >> 3, c = (P & 7) ^ (m & 7);
        async16(qbase + (size_t)m * DM + c * 8, &Qs[P * 8]);
    }
#pragma unroll
    for (int r = 0; r < 2; r++) {
        int P = r * 256 + t;
        int m = P >> 3, c = (P & 7) ^ (m & 7);
        async16(kbase + (size_t)m * DM + c * 8, &Ks[0][P * 8]);
        async16(vbase + (size_t)m * NQ_ + c * 8, &Vs[0][P * 8]);
    }
    asm volatile("s_waitcnt vmcnt(0)" ::: "memory");
    __syncthreads();

    // hoist Q B-frags: col q = w*32 + l31, slice s covers d = s*16 + hi*8 + j
    half8 qf[4];
    {
        int qr = w * 32 + l31;
#pragma unroll
        for (int s = 0; s < 4; s++)
            qf[s] = ((const half8*)Qs)[qr * 8 + ((s * 2 + hi) ^ (qr & 7))];
    }

    floatx16 oacc0, oacc1;   // O^T [64 d][32 q]: d-blocks 0/1
#pragma unroll
    for (int r = 0; r < 16; r++) { oacc0[r] = 0.f; oacc1[r] = 0.f; }
    float lacc = 0.f;

    for (int kt = 0; kt < NTILES; kt++) {
        const int cur = kt & 1;
        asm volatile("s_waitcnt vmcnt(0)" ::: "memory");  // tile-kt loads landed
        __syncthreads();                                  // all waves' slices landed

        if (kt + 1 < NTILES) {   // prefetch tile kt+1 into other buffer
            const int nxt = cur ^ 1;
#pragma unroll
            for (int r = 0; r < 2; r++) {
                int P = r * 256 + t;
                int m = P >> 3, c = (P & 7) ^ (m & 7);
                async16(kbase + (size_t)((kt + 1) * 64 + m) * DM + c * 8, &Ks[nxt][P * 8]);
                async16(vbase + (size_t)m * NQ_ + (kt + 1) * 64 + c * 8, &Vs[nxt][P * 8]);
            }
        }

#pragma unroll
        for (int kh2 = 0; kh2 < 2; kh2++) {
            // S^T[32k x 32q] = K(half) . Q^T : A rows k = kh2*32+l31
            floatx16 sacc;
#pragma unroll
            for (int r = 0; r < 16; r++) sacc[r] = 0.f;
            __builtin_amdgcn_s_setprio(1);
#pragma unroll
            for (int s = 0; s < 4; s++) {
                half8 kf = ((const half8*)Ks[cur])[(kh2 * 32 + l31) * 8 + ((s * 2 + hi) ^ (l31 & 7))];
                sacc = __builtin_amdgcn_mfma_f32_32x32x16_f16(kf, qf[s], sacc, 0, 0, 0);
            }
            __builtin_amdgcn_s_setprio(0);

            // softmax (fixed max): p = exp2(s') (log2e pre-folded into Q)
#pragma unroll
            for (int r = 0; r < 16; r++) sacc[r] = __builtin_amdgcn_exp2f(sacc[r]);
#pragma unroll
            for (int r = 0; r < 16; r++) lacc += sacc[r];

            // P -> PV B-frags in registers via v_permlane32_swap_b32:
            // (u0,u2) = swap(a0,b0), (u1,u3) = swap(a1,b1). Pure VALU, no
            // LDS-pipe roundtrip (was ds_bpermute + 6 selects).
            half8 pf0, pf1;
            {
                unsigned a0 = pkh(sacc[0], sacc[1]),  a1 = pkh(sacc[2], sacc[3]);
                unsigned b0 = pkh(sacc[4], sacc[5]),  b1 = pkh(sacc[6], sacc[7]);
                asm("v_permlane32_swap_b32 %0, %1" : "+v"(a0), "+v"(b0));
                asm("v_permlane32_swap_b32 %0, %1" : "+v"(a1), "+v"(b1));
                union { unsigned u[4]; half8 hh; } pu;
                pu.u[0] = a0; pu.u[1] = a1; pu.u[2] = b0; pu.u[3] = b1;
                pf0 = pu.hh;
            }
            {
                unsigned a0 = pkh(sacc[8], sacc[9]),   a1 = pkh(sacc[10], sacc[11]);
                unsigned b0 = pkh(sacc[12], sacc[13]), b1 = pkh(sacc[14], sacc[15]);
                asm("v_permlane32_swap_b32 %0, %1" : "+v"(a0), "+v"(b0));
                asm("v_permlane32_swap_b32 %0, %1" : "+v"(a1), "+v"(b1));
                union { unsigned u[4]; half8 hh; } pu;
                pu.u[0] = a0; pu.u[1] = a1; pu.u[2] = b0; pu.u[3] = b1;
                pf1 = pu.hh;
            }

            // O^T += V^T[:, kh2-half] . P^T
            __builtin_amdgcn_s_setprio(1);
#pragma unroll
            for (int s2 = 0; s2 < 2; s2++) {
                half8 pfk = s2 ? pf1 : pf0;
                {
                    half8 vf = ((const half8*)Vs[cur])[(0 * 32 + l31) * 8 + ((kh2 * 4 + s2 * 2 + hi) ^ (l31 & 7))];
                    oacc0 = __builtin_amdgcn_mfma_f32_32x32x16_f16(vf, pfk, oacc0, 0, 0, 0);
                }
                {
                    half8 vf = ((const half8*)Vs[cur])[(1 * 32 + l31) * 8 + ((kh2 * 4 + s2 * 2 + hi) ^ (l31 & 7))];
                    oacc1 = __builtin_amdgcn_mfma_f32_32x32x16_f16(vf, pfk, oacc1, 0, 0, 0);
                }
            }
            __builtin_amdgcn_s_setprio(0);
        }
    }

    // epilogue: l = own 32 rows + partner's 32 (lane^32), normalize, store.
    {
        float lt = lacc + __shfl_xor(lacc, 32);
        float linv = 1.f / lt;
        int qrow = b * NQ_ + qt * 128 + w * 32 + l31;
#pragma unroll
        for (int g = 0; g < 4; g++) {
            half4v o0, o1;
#pragma unroll
            for (int j = 0; j < 4; j++) {
                o0[j] = (_Float16)(oacc0[g * 4 + j] * linv);
                o1[j] = (_Float16)(oacc1[g * 4 + j] * linv);
            }
            int d0 = g * 8 + 4 * hi;
            *(half4v*)&Og[(size_t)qrow * DM + h * DH_ + d0] = o0;
            *(half4v*)&Og[(size_t)qrow * DM + h * DH_ + 32 + d0] = o1;
        }
    }
}

// ---------------------------------------------------------------------------
// O projection: out[4096,1024] fp32 = ao @ Wo^T + bo.
// R5: 64x64 tile -> 128x64 (proj-style structure). grid 512 (2/CU), 24KB LDS,
// 4 waves 2x2, wave 64x32 (4x2 of 16x16x32).
// ---------------------------------------------------------------------------
__global__ __launch_bounds__(256, 4) void gemm_o(const _Float16* __restrict__ A,
                                                 const _Float16* __restrict__ W,
                                                 const float* __restrict__ bias,
                                                 float* __restrict__ C) {
    __shared__ _Float16 As[128 * 64];   // 16 KB
    __shared__ _Float16 Bs[64 * 64];    //  8 KB

    const int t = threadIdx.x;
    const int w = t >> 6, lane = t & 63;
    const int r16 = lane & 15, quad = lane >> 4;
    const int blk = blockIdx.x;
    const int bm = (blk & 7) * 4 + ((blk >> 3) & 3);   // 0..31
    const int bn = blk >> 5;                            // 0..15
    const int m0 = bm * 128, n0 = bn * 64;
    const int wm = w >> 1, wn = w & 1;

    floatx4 acc[4][2];
#pragma unroll
    for (int i = 0; i < 4; i++)
#pragma unroll
        for (int j = 0; j < 2; j++)
#pragma unroll
            for (int r = 0; r < 4; r++) acc[i][j][r] = 0.f;

    const int ph0 = quad ^ (r16 & 7), ph1 = ph0 ^ 4;

    for (int k0 = 0; k0 < DM; k0 += 64) {
        __syncthreads();
#pragma unroll
        for (int i = 0; i < 4; i++) {
            int P = i * 256 + t;
            int m = P >> 3, c = (P & 7) ^ (m & 7);
            async16(A + (size_t)(m0 + m) * DM + k0 + c * 8, &As[P * 8]);
        }
#pragma unroll
        for (int i = 0; i < 2; i++) {
            int P = i * 256 + t;
            int m = P >> 3, c = (P & 7) ^ (m & 7);
            async16(W + (size_t)(n0 + m) * DM + k0 + c * 8, &Bs[P * 8]);
        }
        asm volatile("s_waitcnt vmcnt(0)" ::: "memory");
        __syncthreads();

        half8 af[4][2], bf[2][2];
#pragma unroll
        for (int mi = 0; mi < 4; mi++) {
            int m = wm * 64 + mi * 16 + r16;
            af[mi][0] = ((const half8*)As)[m * 8 + ph0];
            af[mi][1] = ((const half8*)As)[m * 8 + ph1];
        }
#pragma unroll
        for (int ni = 0; ni < 2; ni++) {
            int n = wn * 32 + ni * 16 + r16;
            bf[ni][0] = ((const half8*)Bs)[n * 8 + ph0];
            bf[ni][1] = ((const half8*)Bs)[n * 8 + ph1];
        }
#pragma unroll
        for (int kd = 0; kd < 2; kd++)
#pragma unroll
            for (int mi = 0; mi < 4; mi++)
#pragma unroll
                for (int ni = 0; ni < 2; ni++)
                    acc[mi][ni] = __builtin_amdgcn_mfma_f32_16x16x32_f16(
                        af[mi][kd], bf[ni][kd], acc[mi][ni], 0, 0, 0);
    }

#pragma unroll
    for (int mi = 0; mi < 4; mi++)
#pragma unroll
        for (int r = 0; r < 4; r++) {
            int row = m0 + wm * 64 + mi * 16 + quad * 4 + r;
#pragma unroll
            for (int ni = 0; ni < 2; ni++) {
                int col = n0 + wn * 32 + ni * 16 + r16;
                C[(size_t)row * DM + col] = acc[mi][ni][r] + bias[col];
            }
        }
}

// ---------------------------------------------------------------------------
extern "C" void kernel_launch(void* const* d_in, const int* in_sizes, int n_in,
                              void* d_out, int out_size, void* d_ws, size_t ws_size,
                              hipStream_t stream) {
    const float* q  = (const float*)d_in[0];
    const float* kv = (const float*)d_in[1];
    const float* Wq = (const float*)d_in[2];
    const float* bq = (const float*)d_in[3];
    const float* Wk = (const float*)d_in[4];
    const float* bk = (const float*)d_in[5];
    const float* Wv = (const float*)d_in[6];
    const float* bv = (const float*)d_in[7];
    const float* Wo = (const float*)d_in[8];
    const float* bo = (const float*)d_in[9];

    char* ws = (char*)d_ws;
    _Float16* q16  = (_Float16*)(ws);
    _Float16* kv16 = (_Float16*)(ws + (size_t)(8  << 20));
    _Float16* w16q = (_Float16*)(ws + (size_t)(16 << 20));
    _Float16* w16k = (_Float16*)(ws + (size_t)(18 << 20));
    _Float16* w16v = (_Float16*)(ws + (size_t)(20 << 20));
    _Float16* w16o = (_Float16*)(ws + (size_t)(22 << 20));
    _Float16* qh16 = (_Float16*)(ws + (size_t)(24 << 20));
    _Float16* kh16 = (_Float16*)(ws + (size_t)(32 << 20));
    _Float16* vt16 = (_Float16*)(ws + (size_t)(40 << 20));
    _Float16* ao16 = (_Float16*)(ws + (size_t)(48 << 20));

    cvt_all<<<6144, 256, 0, stream>>>(q, kv, Wq, Wk, Wv, Wo,
                                      q16, kv16, w16q, w16k, w16v, w16o);

    proj_qkv<<<768, 256, 0, stream>>>(q16, kv16, w16q, w16k, w16v,
                                      bq, bk, bv, qh16, kh16, vt16);

    attn_mfma<<<512, 256, 0, stream>>>(qh16, kh16, vt16, ao16);

    gemm_o<<<512, 256, 0, stream>>>(ao16, w16o, bo, (float*)d_out);
}

// Round 6
// 196.397 us; speedup vs baseline: 2.0183x; 1.0081x over previous
//
#include <hip/hip_runtime.h>
#include <cstddef>
#include <cstdint>

using half4v   = __attribute__((ext_vector_type(4))) _Float16;
using half8    = __attribute__((ext_vector_type(8))) _Float16;
using floatx4  = __attribute__((ext_vector_type(4))) float;
using floatx16 = __attribute__((ext_vector_type(16))) float;

#define B_   2
#define NQ_  2048
#define DM   1024
#define NH_  16
#define DH_  64
#define NTILES 32   // NKV / 64

// async global->LDS, 16B per lane. LDS dest = wave-uniform base + lane*16.
__device__ __forceinline__ void async16(const _Float16* g, _Float16* l) {
    __builtin_amdgcn_global_load_lds(
        (const __attribute__((address_space(1))) unsigned int*)g,
        (__attribute__((address_space(3))) unsigned int*)l, 16, 0, 0);
}

// RNE pack 2 f32 -> u32 of 2 f16 (matches baseline numerics).
__device__ __forceinline__ unsigned pkh(float a, float b) {
    union { _Float16 h[2]; unsigned u; } x;
    x.h[0] = (_Float16)a; x.h[1] = (_Float16)b;
    return x.u;
}

// ---------------------------------------------------------------------------
// Fused fp32 -> fp16 convert for all 6 tensors (1 launch).
// ---------------------------------------------------------------------------
__global__ __launch_bounds__(256) void cvt_all(
        const float* __restrict__ q,  const float* __restrict__ kv,
        const float* __restrict__ wq, const float* __restrict__ wk,
        const float* __restrict__ wv, const float* __restrict__ wo,
        _Float16* __restrict__ dq,  _Float16* __restrict__ dkv,
        _Float16* __restrict__ dwq, _Float16* __restrict__ dwk,
        _Float16* __restrict__ dwv, _Float16* __restrict__ dwo) {
    int blk = blockIdx.x;
    const float* s;
    _Float16* d;
    int base;
    if (blk < 2048)      { s = q;  d = dq;  base = blk; }
    else if (blk < 4096) { s = kv; d = dkv; base = blk - 2048; }
    else if (blk < 4608) { s = wq; d = dwq; base = blk - 4096; }
    else if (blk < 5120) { s = wk; d = dwk; base = blk - 4608; }
    else if (blk < 5632) { s = wv; d = dwv; base = blk - 5120; }
    else                 { s = wo; d = dwo; base = blk - 5632; }
    int i = base * 256 + threadIdx.x;
    const float4* s4 = (const float4*)s;
    float4 a = s4[2 * i], b = s4[2 * i + 1];
    half8 h;
    h[0] = (_Float16)a.x; h[1] = (_Float16)a.y; h[2] = (_Float16)a.z; h[3] = (_Float16)a.w;
    h[4] = (_Float16)b.x; h[5] = (_Float16)b.y; h[6] = (_Float16)b.z; h[7] = (_Float16)b.w;
    ((half8*)d)[i] = h;
}

// ---------------------------------------------------------------------------
// Fused QKV projection GEMM, 768 blocks (3/CU resident).
// Q scale = 0.125*log2(e) so attn softmax uses bare exp2.
// ---------------------------------------------------------------------------
__global__ __launch_bounds__(256, 3) void proj_qkv(
        const _Float16* __restrict__ q16, const _Float16* __restrict__ kv16,
        const _Float16* __restrict__ wqp, const _Float16* __restrict__ wkp,
        const _Float16* __restrict__ wvp,
        const float* __restrict__ bqp, const float* __restrict__ bkp,
        const float* __restrict__ bvp,
        _Float16* __restrict__ qh, _Float16* __restrict__ kh,
        _Float16* __restrict__ vt) {
    __shared__ _Float16 As[128 * 64];   // 16 KB
    __shared__ _Float16 Bs[128 * 64];   // 16 KB

    const int which = blockIdx.x >> 8;
    const int sub = blockIdx.x & 255;
    const _Float16* A = (which == 0) ? q16 : kv16;
    const _Float16* W = (which == 0) ? wqp : (which == 1) ? wkp : wvp;
    const float* bias = (which == 0) ? bqp : (which == 1) ? bkp : bvp;

    const int t = threadIdx.x;
    const int w = t >> 6, lane = t & 63;
    const int r16 = lane & 15, quad = lane >> 4;
    const int bm = (sub & 7) * 4 + ((sub >> 3) & 3);
    const int bn = sub >> 5;
    const int m0 = bm * 128, n0 = bn * 128;
    const int wm = w >> 1, wn = w & 1;

    floatx4 acc[4][4];
#pragma unroll
    for (int i = 0; i < 4; i++)
#pragma unroll
        for (int j = 0; j < 4; j++)
#pragma unroll
            for (int r = 0; r < 4; r++) acc[i][j][r] = 0.f;

    const int ph0 = quad ^ (r16 & 7), ph1 = ph0 ^ 4;

    for (int k0 = 0; k0 < DM; k0 += 64) {
        __syncthreads();
#pragma unroll
        for (int i = 0; i < 4; i++) {
            int P = i * 256 + t;
            int m = P >> 3, c = (P & 7) ^ (m & 7);
            async16(A + (size_t)(m0 + m) * DM + k0 + c * 8, &As[P * 8]);
            async16(W + (size_t)(n0 + m) * DM + k0 + c * 8, &Bs[P * 8]);
        }
        asm volatile("s_waitcnt vmcnt(0)" ::: "memory");
        __syncthreads();

        half8 af[4][2], bf[4][2];
#pragma unroll
        for (int mi = 0; mi < 4; mi++) {
            int m = wm * 64 + mi * 16 + r16;
            af[mi][0] = ((const half8*)As)[m * 8 + ph0];
            af[mi][1] = ((const half8*)As)[m * 8 + ph1];
        }
#pragma unroll
        for (int ni = 0; ni < 4; ni++) {
            int n = wn * 64 + ni * 16 + r16;
            bf[ni][0] = ((const half8*)Bs)[n * 8 + ph0];
            bf[ni][1] = ((const half8*)Bs)[n * 8 + ph1];
        }
#pragma unroll
        for (int kd = 0; kd < 2; kd++)
#pragma unroll
            for (int mi = 0; mi < 4; mi++)
#pragma unroll
                for (int ni = 0; ni < 4; ni++)
                    acc[mi][ni] = __builtin_amdgcn_mfma_f32_16x16x32_f16(
                        af[mi][kd], bf[ni][kd], acc[mi][ni], 0, 0, 0);
    }

    if (which < 2) {
        _Float16* C = (which == 0) ? qh : kh;
        // 0.125 * log2(e): softmax downstream uses exp2 directly.
        const float esc = (which == 0) ? 0.18033688011112042f : 1.0f;
#pragma unroll
        for (int mi = 0; mi < 4; mi++)
#pragma unroll
            for (int r = 0; r < 4; r++) {
                int row = m0 + wm * 64 + mi * 16 + quad * 4 + r;
#pragma unroll
                for (int ni = 0; ni < 4; ni++) {
                    int col = n0 + wn * 64 + ni * 16 + r16;
                    C[(size_t)row * DM + col] = (_Float16)((acc[mi][ni][r] + bias[col]) * esc);
                }
            }
    } else {
#pragma unroll
        for (int mi = 0; mi < 4; mi++) {
            int krow = m0 + wm * 64 + mi * 16 + quad * 4;
            int bb = krow >> 11, kk = krow & 2047;
#pragma unroll
            for (int ni = 0; ni < 4; ni++) {
                int col = n0 + wn * 64 + ni * 16 + r16;
                int hh = col >> 6, dd = col & 63;
                float bv = bias[col];
                half4v pk;
#pragma unroll
                for (int r = 0; r < 4; r++) pk[r] = (_Float16)(acc[mi][ni][r] + bv);
                *(half4v*)&vt[((size_t)((bb * NH_ + hh) * DH_ + dd)) * NQ_ + kk] = pk;
            }
        }
    }
}

// ---------------------------------------------------------------------------
// Flash attention, fixed-max softmax. R6: counted-vmcnt 3-deep K/V ring.
// Evidence R0-R5: 63us glued across 4 structures; R5's chain-VALU cut gave
// -10% (56.6us). The remaining untouched poison: per-tile vmcnt(0) drain +
// 2 barriers (the m233 "2-phase stall"; m218: counted-vs-drain0 = +38-73%).
// This round: Ks/Vs -> 3 buffers; loads for tile t+2 issued AFTER the iter-t
// barrier (all waves finished reading buf (t-1)%3 == (t+2)%3 -> race-free);
// before consuming tile t: s_waitcnt vmcnt(4) (only t+1's 4 loads may remain
// in flight; each thread waits for its OWN t-loads, barrier makes all
// threads' visible). Never drains to 0 in the main loop; last iter peeled.
// ONE barrier per tile (was 2 + full drain).
// Geometry/numerics unchanged from R5: 4 waves, 32q x 64k/wave, 32x32x16
// MFMA, P in regs via permlane32_swap, exp2 softmax, grid 512.
// LDS: Qs 16KB + Ks 3x8KB + Vs 3x8KB = 64KB -> 2 blocks/CU (grid-capped).
// ---------------------------------------------------------------------------
__global__ __launch_bounds__(256, 4) void attn_mfma(const _Float16* __restrict__ Qg,
                                                    const _Float16* __restrict__ Kg,
                                                    const _Float16* __restrict__ Vt,
                                                    _Float16* __restrict__ Og) {
    __shared__ _Float16 Qs[128 * 64];    // 16 KB: [128 q][64 d], chunk^(q&7)
    __shared__ _Float16 Ks[3][64 * 64];  // 24 KB: [64 k][64 d], chunk^(k&7)
    __shared__ _Float16 Vs[3][64 * 64];  // 24 KB: [64 d][64 k], chunk^(d&7)

    const int t = threadIdx.x, w = t >> 6, lane = t & 63;
    const int l31 = lane & 31, hi = lane >> 5;
    const int blk = blockIdx.x;
    const int bh = (blk & 7) * 4 + ((blk >> 3) & 3);
    const int qt = blk >> 5;                      // 0..15 (128 q rows each)
    const int b = bh >> 4, h = bh & 15;

    const _Float16* qbase = Qg + (size_t)(b * NQ_ + qt * 128) * DM + h * DH_;
    const _Float16* kbase = Kg + (size_t)(b * NQ_) * DM + h * DH_;
    const _Float16* vbase = Vt + (size_t)bh * DH_ * NQ_;

    // prologue: issue Q (4 rounds), then K0/V0, then K1/V1 -> 12 outstanding.
#pragma unroll
    for (int r = 0; r < 4; r++) {
        int P = r * 256 + t;
        int m = P >> 3, c = (P & 7) ^ (m & 7);
        async16(qbase + (size_t)m * DM + c * 8, &Qs[P * 8]);
    }
#pragma unroll
    for (int r = 0; r < 2; r++) {
        int P = r * 256 + t;
        int m = P >> 3, c = (P & 7) ^ (m & 7);
        async16(kbase + (size_t)m * DM + c * 8, &Ks[0][P * 8]);
        async16(vbase + (size_t)m * NQ_ + c * 8, &Vs[0][P * 8]);
    }
#pragma unroll
    for (int r = 0; r < 2; r++) {
        int P = r * 256 + t;
        int m = P >> 3, c = (P & 7) ^ (m & 7);
        async16(kbase + (size_t)(64 + m) * DM + c * 8, &Ks[1][P * 8]);
        async16(vbase + (size_t)m * NQ_ + 64 + c * 8, &Vs[1][P * 8]);
    }
    // Q landed (oldest 4 of 12); K1/V1 may still fly.
    asm volatile("s_waitcnt vmcnt(8)" ::: "memory");
    asm volatile("s_barrier" ::: "memory");

    // hoist Q B-frags: col q = w*32 + l31, slice s covers d = s*16 + hi*8 + j
    half8 qf[4];
    {
        int qr = w * 32 + l31;
#pragma unroll
        for (int s = 0; s < 4; s++)
            qf[s] = ((const half8*)Qs)[qr * 8 + ((s * 2 + hi) ^ (qr & 7))];
    }

    floatx16 oacc0, oacc1;   // O^T [64 d][32 q]: d-blocks 0/1
#pragma unroll
    for (int r = 0; r < 16; r++) { oacc0[r] = 0.f; oacc1[r] = 0.f; }
    float lacc = 0.f;

    // per-tile compute (reads Ks[cur]/Vs[cur]; body identical to R5)
    auto tile = [&](int cur) {
#pragma unroll
        for (int kh2 = 0; kh2 < 2; kh2++) {
            floatx16 sacc;
#pragma unroll
            for (int r = 0; r < 16; r++) sacc[r] = 0.f;
            __builtin_amdgcn_s_setprio(1);
#pragma unroll
            for (int s = 0; s < 4; s++) {
                half8 kf = ((const half8*)Ks[cur])[(kh2 * 32 + l31) * 8 + ((s * 2 + hi) ^ (l31 & 7))];
                sacc = __builtin_amdgcn_mfma_f32_32x32x16_f16(kf, qf[s], sacc, 0, 0, 0);
            }
            __builtin_amdgcn_s_setprio(0);

            // softmax (fixed max): p = exp2(s') (log2e pre-folded into Q)
#pragma unroll
            for (int r = 0; r < 16; r++) sacc[r] = __builtin_amdgcn_exp2f(sacc[r]);
#pragma unroll
            for (int r = 0; r < 16; r++) lacc += sacc[r];

            // P -> PV B-frags in registers via v_permlane32_swap_b32.
            half8 pf0, pf1;
            {
                unsigned a0 = pkh(sacc[0], sacc[1]),  a1 = pkh(sacc[2], sacc[3]);
                unsigned b0 = pkh(sacc[4], sacc[5]),  b1 = pkh(sacc[6], sacc[7]);
                asm("v_permlane32_swap_b32 %0, %1" : "+v"(a0), "+v"(b0));
                asm("v_permlane32_swap_b32 %0, %1" : "+v"(a1), "+v"(b1));
                union { unsigned u[4]; half8 hh; } pu;
                pu.u[0] = a0; pu.u[1] = a1; pu.u[2] = b0; pu.u[3] = b1;
                pf0 = pu.hh;
            }
            {
                unsigned a0 = pkh(sacc[8], sacc[9]),   a1 = pkh(sacc[10], sacc[11]);
                unsigned b0 = pkh(sacc[12], sacc[13]), b1 = pkh(sacc[14], sacc[15]);
                asm("v_permlane32_swap_b32 %0, %1" : "+v"(a0), "+v"(b0));
                asm("v_permlane32_swap_b32 %0, %1" : "+v"(a1), "+v"(b1));
                union { unsigned u[4]; half8 hh; } pu;
                pu.u[0] = a0; pu.u[1] = a1; pu.u[2] = b0; pu.u[3] = b1;
                pf1 = pu.hh;
            }

            // O^T += V^T[:, kh2-half] . P^T
            __builtin_amdgcn_s_setprio(1);
#pragma unroll
            for (int s2 = 0; s2 < 2; s2++) {
                half8 pfk = s2 ? pf1 : pf0;
                {
                    half8 vf = ((const half8*)Vs[cur])[(0 * 32 + l31) * 8 + ((kh2 * 4 + s2 * 2 + hi) ^ (l31 & 7))];
                    oacc0 = __builtin_amdgcn_mfma_f32_32x32x16_f16(vf, pfk, oacc0, 0, 0, 0);
                }
                {
                    half8 vf = ((const half8*)Vs[cur])[(1 * 32 + l31) * 8 + ((kh2 * 4 + s2 * 2 + hi) ^ (l31 & 7))];
                    oacc1 = __builtin_amdgcn_mfma_f32_32x32x16_f16(vf, pfk, oacc1, 0, 0, 0);
                }
            }
            __builtin_amdgcn_s_setprio(0);
        }
    };

    int cur = 0, pre = 2;   // pre = (kt+2)%3
    for (int kt = 0; kt < NTILES - 1; ++kt) {
        // tile kt landed for THIS thread (only kt+1's 4 loads may remain);
        // barrier -> landed for ALL threads, and all reads of buf pre done.
        asm volatile("s_waitcnt vmcnt(4)" ::: "memory");
        asm volatile("s_barrier" ::: "memory");
        if (kt + 2 < NTILES) {
#pragma unroll
            for (int r = 0; r < 2; r++) {
                int P = r * 256 + t;
                int m = P >> 3, c = (P & 7) ^ (m & 7);
                async16(kbase + (size_t)((kt + 2) * 64 + m) * DM + c * 8, &Ks[pre][P * 8]);
                async16(vbase + (size_t)m * NQ_ + (kt + 2) * 64 + c * 8, &Vs[pre][P * 8]);
            }
        }
        tile(cur);
        cur = (cur == 2) ? 0 : cur + 1;
        pre = (pre == 2) ? 0 : pre + 1;
    }
    // last tile: nothing in flight behind it -> full drain once.
    asm volatile("s_waitcnt vmcnt(0)" ::: "memory");
    asm volatile("s_barrier" ::: "memory");
    tile(cur);

    // epilogue: l = own 32 rows + partner's 32 (lane^32), normalize, store.
    {
        float lt = lacc + __shfl_xor(lacc, 32);
        float linv = 1.f / lt;
        int qrow = b * NQ_ + qt * 128 + w * 32 + l31;
#pragma unroll
        for (int g = 0; g < 4; g++) {
            half4v o0, o1;
#pragma unroll
            for (int j = 0; j < 4; j++) {
                o0[j] = (_Float16)(oacc0[g * 4 + j] * linv);
                o1[j] = (_Float16)(oacc1[g * 4 + j] * linv);
            }
            int d0 = g * 8 + 4 * hi;
            *(half4v*)&Og[(size_t)qrow * DM + h * DH_ + d0] = o0;
            *(half4v*)&Og[(size_t)qrow * DM + h * DH_ + 32 + d0] = o1;
        }
    }
}

// ---------------------------------------------------------------------------
// O projection: out[4096,1024] fp32 = ao @ Wo^T + bo. 128x64 tile, grid 512.
// ---------------------------------------------------------------------------
__global__ __launch_bounds__(256, 4) void gemm_o(const _Float16* __restrict__ A,
                                                 const _Float16* __restrict__ W,
                                                 const float* __restrict__ bias,
                                                 float* __restrict__ C) {
    __shared__ _Float16 As[128 * 64];   // 16 KB
    __shared__ _Float16 Bs[64 * 64];    //  8 KB

    const int t = threadIdx.x;
    const int w = t >> 6, lane = t & 63;
    const int r16 = lane & 15, quad = lane >> 4;
    const int blk = blockIdx.x;
    const int bm = (blk & 7) * 4 + ((blk >> 3) & 3);   // 0..31
    const int bn = blk >> 5;                            // 0..15
    const int m0 = bm * 128, n0 = bn * 64;
    const int wm = w >> 1, wn = w & 1;

    floatx4 acc[4][2];
#pragma unroll
    for (int i = 0; i < 4; i++)
#pragma unroll
        for (int j = 0; j < 2; j++)
#pragma unroll
            for (int r = 0; r < 4; r++) acc[i][j][r] = 0.f;

    const int ph0 = quad ^ (r16 & 7), ph1 = ph0 ^ 4;

    for (int k0 = 0; k0 < DM; k0 += 64) {
        __syncthreads();
#pragma unroll
        for (int i = 0; i < 4; i++) {
            int P = i * 256 + t;
            int m = P >> 3, c = (P & 7) ^ (m & 7);
            async16(A + (size_t)(m0 + m) * DM + k0 + c * 8, &As[P * 8]);
        }
#pragma unroll
        for (int i = 0; i < 2; i++) {
            int P = i * 256 + t;
            int m = P >> 3, c = (P & 7) ^ (m & 7);
            async16(W + (size_t)(n0 + m) * DM + k0 + c * 8, &Bs[P * 8]);
        }
        asm volatile("s_waitcnt vmcnt(0)" ::: "memory");
        __syncthreads();

        half8 af[4][2], bf[2][2];
#pragma unroll
        for (int mi = 0; mi < 4; mi++) {
            int m = wm * 64 + mi * 16 + r16;
            af[mi][0] = ((const half8*)As)[m * 8 + ph0];
            af[mi][1] = ((const half8*)As)[m * 8 + ph1];
        }
#pragma unroll
        for (int ni = 0; ni < 2; ni++) {
            int n = wn * 32 + ni * 16 + r16;
            bf[ni][0] = ((const half8*)Bs)[n * 8 + ph0];
            bf[ni][1] = ((const half8*)Bs)[n * 8 + ph1];
        }
#pragma unroll
        for (int kd = 0; kd < 2; kd++)
#pragma unroll
            for (int mi = 0; mi < 4; mi++)
#pragma unroll
                for (int ni = 0; ni < 2; ni++)
                    acc[mi][ni] = __builtin_amdgcn_mfma_f32_16x16x32_f16(
                        af[mi][kd], bf[ni][kd], acc[mi][ni], 0, 0, 0);
    }

#pragma unroll
    for (int mi = 0; mi < 4; mi++)
#pragma unroll
        for (int r = 0; r < 4; r++) {
            int row = m0 + wm * 64 + mi * 16 + quad * 4 + r;
#pragma unroll
            for (int ni = 0; ni < 2; ni++) {
                int col = n0 + wn * 32 + ni * 16 + r16;
                C[(size_t)row * DM + col] = acc[mi][ni][r] + bias[col];
            }
        }
}

// ---------------------------------------------------------------------------
extern "C" void kernel_launch(void* const* d_in, const int* in_sizes, int n_in,
                              void* d_out, int out_size, void* d_ws, size_t ws_size,
                              hipStream_t stream) {
    const float* q  = (const float*)d_in[0];
    const float* kv = (const float*)d_in[1];
    const float* Wq = (const float*)d_in[2];
    const float* bq = (const float*)d_in[3];
    const float* Wk = (const float*)d_in[4];
    const float* bk = (const float*)d_in[5];
    const float* Wv = (const float*)d_in[6];
    const float* bv = (const float*)d_in[7];
    const float* Wo = (const float*)d_in[8];
    const float* bo = (const float*)d_in[9];

    char* ws = (char*)d_ws;
    _Float16* q16  = (_Float16*)(ws);
    _Float16* kv16 = (_Float16*)(ws + (size_t)(8  << 20));
    _Float16* w16q = (_Float16*)(ws + (size_t)(16 << 20));
    _Float16* w16k = (_Float16*)(ws + (size_t)(18 << 20));
    _Float16* w16v = (_Float16*)(ws + (size_t)(20 << 20));
    _Float16* w16o = (_Float16*)(ws + (size_t)(22 << 20));
    _Float16* qh16 = (_Float16*)(ws + (size_t)(24 << 20));
    _Float16* kh16 = (_Float16*)(ws + (size_t)(32 << 20));
    _Float16* vt16 = (_Float16*)(ws + (size_t)(40 << 20));
    _Float16* ao16 = (_Float16*)(ws + (size_t)(48 << 20));

    cvt_all<<<6144, 256, 0, stream>>>(q, kv, Wq, Wk, Wv, Wo,
                                      q16, kv16, w16q, w16k, w16v, w16o);

    proj_qkv<<<768, 256, 0, stream>>>(q16, kv16, w16q, w16k, w16v,
                                      bq, bk, bv, qh16, kh16, vt16);

    attn_mfma<<<512, 256, 0, stream>>>(qh16, kh16, vt16, ao16);

    gemm_o<<<512, 256, 0, stream>>>(ao16, w16o, bo, (float*)d_out);
}